// Round 1
// baseline (397.600 us; speedup 1.0000x reference)
//
#include <hip/hip_runtime.h>

#define NQ   64
#define CCH  1024
#define DSP  1024      // 32*32 spatial
#define NSUP 25600     // 25*32*32
#define KSLICES 8
#define NK_COV 50      // 25600/8/64

typedef __attribute__((ext_vector_type(4))) float f32x4;
typedef __attribute__((ext_vector_type(8))) __bf16 bf16x8;

__device__ inline unsigned short f2bf(float x) {
  unsigned u = __builtin_bit_cast(unsigned, x);
  u += 0x7fffu + ((u >> 16) & 1u);
  return (unsigned short)(u >> 16);
}

// ---------------- prep kernels ----------------

// one block per channel c: mean over 25600 support elems, then (optionally)
// write centered bf16 row Sb[c][k], k = b*1024 + s
__global__ __launch_bounds__(256) void mean_center_kernel(
    const float* __restrict__ sup, float* __restrict__ mean,
    unsigned short* __restrict__ Sb, int write_sb) {
  const int c = blockIdx.x;
  const int tid = threadIdx.x;
  float s = 0.f;
  for (int qd = tid; qd < 6400; qd += 256) {
    const int b = qd >> 8, s4 = (qd & 255) << 2;
    const float4 v = *(const float4*)(sup + ((size_t)b * CCH + c) * DSP + s4);
    s += v.x + v.y + v.z + v.w;
  }
  __shared__ float red[256];
  red[tid] = s;
  __syncthreads();
  for (int st = 128; st > 0; st >>= 1) {
    if (tid < st) red[tid] += red[tid + st];
    __syncthreads();
  }
  const float m = red[0] * (1.0f / 25600.0f);
  if (tid == 0) mean[c] = m;
  if (write_sb) {
    for (int qd = tid; qd < 6400; qd += 256) {
      const int b = qd >> 8, s4 = (qd & 255) << 2;
      const float4 v = *(const float4*)(sup + ((size_t)b * CCH + c) * DSP + s4);
      ushort4 o;
      o.x = f2bf(v.x - m); o.y = f2bf(v.y - m);
      o.z = f2bf(v.z - m); o.w = f2bf(v.w - m);
      *(ushort4*)(Sb + (size_t)c * NSUP + b * DSP + s4) = o;
    }
  }
}

// one wave per (n,c) row of 1024: L2 norm factor, optionally write bf16 Qb
__global__ __launch_bounds__(256) void qnorm_kernel(
    const float* __restrict__ q, float* __restrict__ qfac,
    unsigned short* __restrict__ Qb, int write_qb) {
  const int row = blockIdx.x * 4 + (threadIdx.x >> 6);
  const int l = threadIdx.x & 63;
  const float4* src = (const float4*)(q + (size_t)row * DSP);
  float4 v[4];
  float ss = 0.f;
#pragma unroll
  for (int i = 0; i < 4; ++i) {
    v[i] = src[l + 64 * i];
    ss += v[i].x * v[i].x + v[i].y * v[i].y + v[i].z * v[i].z + v[i].w * v[i].w;
  }
#pragma unroll
  for (int off = 32; off > 0; off >>= 1) ss += __shfl_xor(ss, off);
  const float f = 1.0f / (sqrtf(ss) + 1e-8f);
  if (l == 0) qfac[row] = f;
  if (write_qb) {
#pragma unroll
    for (int i = 0; i < 4; ++i) {
      ushort4 o;
      o.x = f2bf(v[i].x * f); o.y = f2bf(v[i].y * f);
      o.z = f2bf(v[i].z * f); o.w = f2bf(v[i].w * f);
      *(ushort4*)(Qb + (size_t)row * DSP + (size_t)(l + 64 * i) * 4) = o;
    }
  }
}

// ---------------- GEMM building blocks ----------------

// stage a 128x64 bf16 tile (row-major, ld elems) into linear LDS [128][64]
// via global_load_lds width 16: lds dest is wave-uniform base + lane*16
__device__ inline void stage_glds(const unsigned short* __restrict__ src, int ld,
                                  int row0, int k0, unsigned short* lds) {
  const int tid = threadIdx.x;
  const int w = tid >> 6;
#pragma unroll
  for (int it = 0; it < 4; ++it) {
    const int ci = it * 256 + tid;          // chunk 0..1023 (16B each)
    const int r = ci >> 3, kc = (ci & 7) << 3;
    const unsigned short* g = src + (size_t)(row0 + r) * ld + k0 + kc;
    unsigned short* lb = lds + ((it * 256 + w * 64) << 3);  // wave-uniform
    __builtin_amdgcn_global_load_lds((const __attribute__((address_space(1))) void*)g,
                                     (__attribute__((address_space(3))) void*)lb,
                                     16, 0, 0);
  }
}

// compact-path staging: centered support from fp32
__device__ inline void stage_sup_f32(const float* __restrict__ sup,
                                     const float* __restrict__ mean,
                                     int row0, int k0, unsigned short* lds) {
  const int tid = threadIdx.x;
#pragma unroll
  for (int it = 0; it < 4; ++it) {
    const int ci = it * 256 + tid;
    const int r = ci >> 3, kc = (ci & 7) << 3;
    const int c = row0 + r;
    const int k = k0 + kc;
    const int b = k >> 10, sp = k & 1023;
    const float4* g = (const float4*)(sup + ((size_t)b * CCH + c) * DSP + sp);
    const float4 v0 = g[0], v1 = g[1];
    const float m = mean[c];
    union { unsigned short h[8]; int4 q; } pk;
    pk.h[0] = f2bf(v0.x - m); pk.h[1] = f2bf(v0.y - m);
    pk.h[2] = f2bf(v0.z - m); pk.h[3] = f2bf(v0.w - m);
    pk.h[4] = f2bf(v1.x - m); pk.h[5] = f2bf(v1.y - m);
    pk.h[6] = f2bf(v1.z - m); pk.h[7] = f2bf(v1.w - m);
    *(int4*)(lds + (size_t)ci * 8) = pk.q;
  }
}

// compact-path staging: normalized query from fp32
__device__ inline void stage_q_f32(const float* __restrict__ qn,
                                   const float* __restrict__ qfacn,
                                   int row0, int k0, unsigned short* lds) {
  const int tid = threadIdx.x;
#pragma unroll
  for (int it = 0; it < 4; ++it) {
    const int ci = it * 256 + tid;
    const int r = ci >> 3, kc = (ci & 7) << 3;
    const int c = row0 + r;
    const float4* g = (const float4*)(qn + (size_t)c * DSP + k0 + kc);
    const float4 v0 = g[0], v1 = g[1];
    const float f = qfacn[c];
    union { unsigned short h[8]; int4 q; } pk;
    pk.h[0] = f2bf(v0.x * f); pk.h[1] = f2bf(v0.y * f);
    pk.h[2] = f2bf(v0.z * f); pk.h[3] = f2bf(v0.w * f);
    pk.h[4] = f2bf(v1.x * f); pk.h[5] = f2bf(v1.y * f);
    pk.h[6] = f2bf(v1.z * f); pk.h[7] = f2bf(v1.w * f);
    *(int4*)(lds + (size_t)ci * 8) = pk.q;
  }
}

// one BK=64 compute step: 32 MFMAs per wave on 64x64 out sub-tile
__device__ inline void compute_step(const unsigned short* lA, const unsigned short* lB,
                                    int wr, int wc, int lr, int kg, f32x4 acc[4][4]) {
#pragma unroll
  for (int kk = 0; kk < 64; kk += 32) {
    bf16x8 a[4], b[4];
#pragma unroll
    for (int i = 0; i < 4; ++i)
      a[i] = *(const bf16x8*)(const void*)(lA + (wr + i * 16 + lr) * 64 + kk + kg);
#pragma unroll
    for (int j = 0; j < 4; ++j)
      b[j] = *(const bf16x8*)(const void*)(lB + (wc + j * 16 + lr) * 64 + kk + kg);
#pragma unroll
    for (int i = 0; i < 4; ++i)
#pragma unroll
      for (int j = 0; j < 4; ++j)
        acc[i][j] = __builtin_amdgcn_mfma_f32_16x16x32_bf16(a[i], b[j], acc[i][j], 0, 0, 0);
  }
}

__device__ inline void decode_tile(int t, int& ti, int& tj) {
  int rem = t; ti = 0;
  while (rem >= 8 - ti) { rem -= 8 - ti; ++ti; }
  tj = ti + rem;
}

// ---------------- cov = centered @ centered^T / (N-1+eps), upper tiles only ----------------
template <bool F32>
__global__ __launch_bounds__(256) void cov_kernel(
    const unsigned short* __restrict__ Sb, const float* __restrict__ sup,
    const float* __restrict__ mean, float* __restrict__ cov) {
  __shared__ unsigned short lA[128 * 64];
  __shared__ unsigned short lB[128 * 64];
  int ti, tj; decode_tile(blockIdx.x, ti, tj);
  const int ks = blockIdx.y;
  const int tid = threadIdx.x, l = tid & 63, w = tid >> 6;
  const int wr = (w >> 1) * 64, wc = (w & 1) * 64, lr = l & 15, kg = (l >> 4) * 8;
  f32x4 acc[4][4];
#pragma unroll
  for (int i = 0; i < 4; ++i)
#pragma unroll
    for (int j = 0; j < 4; ++j) acc[i][j] = 0.f;

  for (int kt = 0; kt < NK_COV; ++kt) {
    const int k0 = ks * (NSUP / KSLICES) + kt * 64;
    if (F32) {
      stage_sup_f32(sup, mean, ti * 128, k0, lA);
      stage_sup_f32(sup, mean, tj * 128, k0, lB);
    } else {
      stage_glds(Sb, NSUP, ti * 128, k0, lA);
      stage_glds(Sb, NSUP, tj * 128, k0, lB);
    }
    __syncthreads();
    compute_step(lA, lB, wr, wc, lr, kg, acc);
    __syncthreads();
  }
  const float scale = 1.0f / (25599.0f + 1e-8f);
  const int rbase = ti * 128 + wr + (l >> 4) * 4;
  const int cbase = tj * 128 + wc + (l & 15);
#pragma unroll
  for (int i = 0; i < 4; ++i)
#pragma unroll
    for (int j = 0; j < 4; ++j)
#pragma unroll
      for (int r = 0; r < 4; ++r)
        atomicAdd(&cov[(size_t)(rbase + i * 16 + r) * CCH + cbase + j * 16],
                  acc[i][j][r] * scale);
}

// ---------------- per-query Gram GEMM fused with cov Frobenius product ----------------
template <bool F32>
__global__ __launch_bounds__(256) void gram_kernel(
    const unsigned short* __restrict__ Qb, const float* __restrict__ q,
    const float* __restrict__ qfac, const float* __restrict__ cov,
    float* __restrict__ out) {
  __shared__ unsigned short lA[128 * 64];
  __shared__ unsigned short lB[128 * 64];
  int ti, tj; decode_tile(blockIdx.x, ti, tj);
  const int n = blockIdx.y;
  const int tid = threadIdx.x, l = tid & 63, w = tid >> 6;
  const int wr = (w >> 1) * 64, wc = (w & 1) * 64, lr = l & 15, kg = (l >> 4) * 8;
  f32x4 acc[4][4];
#pragma unroll
  for (int i = 0; i < 4; ++i)
#pragma unroll
    for (int j = 0; j < 4; ++j) acc[i][j] = 0.f;

  const unsigned short* Qn = Qb + (size_t)n * CCH * DSP;
  const float* qn = q + (size_t)n * CCH * DSP;
  const float* qfacn = qfac + (size_t)n * CCH;

  for (int kt = 0; kt < 16; ++kt) {
    const int k0 = kt * 64;
    if (F32) {
      stage_q_f32(qn, qfacn, ti * 128, k0, lA);
      stage_q_f32(qn, qfacn, tj * 128, k0, lB);
    } else {
      stage_glds(Qn, DSP, ti * 128, k0, lA);
      stage_glds(Qn, DSP, tj * 128, k0, lB);
    }
    __syncthreads();
    compute_step(lA, lB, wr, wc, lr, kg, acc);
    __syncthreads();
  }
  float s = 0.f;
  const int rbase = ti * 128 + wr + (l >> 4) * 4;
  const int cbase = tj * 128 + wc + (l & 15);
#pragma unroll
  for (int i = 0; i < 4; ++i)
#pragma unroll
    for (int j = 0; j < 4; ++j)
#pragma unroll
      for (int r = 0; r < 4; ++r)
        s += acc[i][j][r] * cov[(size_t)(rbase + i * 16 + r) * CCH + cbase + j * 16];
  if (ti != tj) s *= 2.0f;
  s *= (1.0f / 1024.0f);
#pragma unroll
  for (int off = 32; off > 0; off >>= 1) s += __shfl_xor(s, off);
  if (l == 0) atomicAdd(&out[n], s);
}

// ---------------- launch ----------------
extern "C" void kernel_launch(void* const* d_in, const int* in_sizes, int n_in,
                              void* d_out, int out_size, void* d_ws, size_t ws_size,
                              hipStream_t stream) {
  const float* q = (const float*)d_in[0];
  const float* sup = (const float*)d_in[1];
  float* out = (float*)d_out;

  char* ws = (char*)d_ws;
  float* mean = (float*)ws;                                  // 4 KB
  float* qfac = (float*)(ws + (4 << 10));                    // 256 KB
  float* cov  = (float*)(ws + (4 << 10) + (256 << 10));      // 4 MB
  unsigned short* Sb = (unsigned short*)(ws + (4 << 10) + (256 << 10) + (4 << 20));
  unsigned short* Qb = Sb + (size_t)CCH * NSUP;
  const size_t need_fat = (size_t)(4 << 10) + (256 << 10) + (4 << 20) +
                          (size_t)CCH * NSUP * 2 + (size_t)NQ * CCH * DSP * 2;
  const bool fat = ws_size >= need_fat;

  hipMemsetAsync(out, 0, (size_t)out_size * sizeof(float), stream);
  hipMemsetAsync(cov, 0, (size_t)CCH * CCH * sizeof(float), stream);

  mean_center_kernel<<<CCH, 256, 0, stream>>>(sup, mean, Sb, fat ? 1 : 0);
  qnorm_kernel<<<NQ * CCH / 4, 256, 0, stream>>>(q, qfac, Qb, fat ? 1 : 0);

  if (fat) {
    cov_kernel<false><<<dim3(36, KSLICES), 256, 0, stream>>>(Sb, sup, mean, cov);
    gram_kernel<false><<<dim3(36, NQ), 256, 0, stream>>>(Qb, q, qfac, cov, out);
  } else {
    cov_kernel<true><<<dim3(36, KSLICES), 256, 0, stream>>>(Sb, sup, mean, cov);
    gram_kernel<true><<<dim3(36, NQ), 256, 0, stream>>>(Qb, q, qfac, cov, out);
  }
}

// Round 2
// 341.181 us; speedup vs baseline: 1.1654x; 1.1654x over previous
//
#include <hip/hip_runtime.h>

#define NQ   64
#define CCH  1024
#define DSP  1024      // 32*32 spatial
#define NSUP 25600     // 25*32*32
#define KSLICES 8
#define NK_COV 50      // 25600/8/64

typedef __attribute__((ext_vector_type(4))) float f32x4;
typedef __attribute__((ext_vector_type(8))) __bf16 bf16x8;

__device__ inline unsigned short f2bf(float x) {
  unsigned u = __builtin_bit_cast(unsigned, x);
  u += 0x7fffu + ((u >> 16) & 1u);
  return (unsigned short)(u >> 16);
}

// ---------------- prep kernels ----------------

// one block per channel c: mean over 25600 support elems, then (optionally)
// write centered bf16 row Sb[c][k], k = b*1024 + s
__global__ __launch_bounds__(256) void mean_center_kernel(
    const float* __restrict__ sup, float* __restrict__ mean,
    unsigned short* __restrict__ Sb, int write_sb) {
  const int c = blockIdx.x;
  const int tid = threadIdx.x;
  float s = 0.f;
  for (int qd = tid; qd < 6400; qd += 256) {
    const int b = qd >> 8, s4 = (qd & 255) << 2;
    const float4 v = *(const float4*)(sup + ((size_t)b * CCH + c) * DSP + s4);
    s += v.x + v.y + v.z + v.w;
  }
  __shared__ float red[256];
  red[tid] = s;
  __syncthreads();
  for (int st = 128; st > 0; st >>= 1) {
    if (tid < st) red[tid] += red[tid + st];
    __syncthreads();
  }
  const float m = red[0] * (1.0f / 25600.0f);
  if (tid == 0) mean[c] = m;
  if (write_sb) {
    for (int qd = tid; qd < 6400; qd += 256) {
      const int b = qd >> 8, s4 = (qd & 255) << 2;
      const float4 v = *(const float4*)(sup + ((size_t)b * CCH + c) * DSP + s4);
      ushort4 o;
      o.x = f2bf(v.x - m); o.y = f2bf(v.y - m);
      o.z = f2bf(v.z - m); o.w = f2bf(v.w - m);
      *(ushort4*)(Sb + (size_t)c * NSUP + b * DSP + s4) = o;
    }
  }
}

// one wave per (n,c) row of 1024: L2 norm factor, optionally write bf16 Qb
__global__ __launch_bounds__(256) void qnorm_kernel(
    const float* __restrict__ q, float* __restrict__ qfac,
    unsigned short* __restrict__ Qb, int write_qb) {
  const int row = blockIdx.x * 4 + (threadIdx.x >> 6);
  const int l = threadIdx.x & 63;
  const float4* src = (const float4*)(q + (size_t)row * DSP);
  float4 v[4];
  float ss = 0.f;
#pragma unroll
  for (int i = 0; i < 4; ++i) {
    v[i] = src[l + 64 * i];
    ss += v[i].x * v[i].x + v[i].y * v[i].y + v[i].z * v[i].z + v[i].w * v[i].w;
  }
#pragma unroll
  for (int off = 32; off > 0; off >>= 1) ss += __shfl_xor(ss, off);
  const float f = 1.0f / (sqrtf(ss) + 1e-8f);
  if (l == 0) qfac[row] = f;
  if (write_qb) {
#pragma unroll
    for (int i = 0; i < 4; ++i) {
      ushort4 o;
      o.x = f2bf(v[i].x * f); o.y = f2bf(v[i].y * f);
      o.z = f2bf(v[i].z * f); o.w = f2bf(v[i].w * f);
      *(ushort4*)(Qb + (size_t)row * DSP + (size_t)(l + 64 * i) * 4) = o;
    }
  }
}

// ---------------- GEMM building blocks ----------------
// LDS layout: [128 rows][64 cols] bf16, XOR-swizzled: LDS[row][c ^ ((row&7)<<3)]
// holds logical (row, c). global_load_lds writes linearly, so the SOURCE column
// is pre-swizzled (rule #21: both-sides-or-neither).

// stage a 128x64 bf16 tile (row-major, ld elems) into swizzled LDS
__device__ inline void stage_glds(const unsigned short* __restrict__ src, int ld,
                                  int row0, int k0, unsigned short* lds) {
  const int tid = threadIdx.x;
  const int w = tid >> 6;
#pragma unroll
  for (int it = 0; it < 4; ++it) {
    const int ci = it * 256 + tid;          // chunk 0..1023 (16B each)
    const int r = ci >> 3;
    const int kc = ((ci & 7) ^ (r & 7)) << 3;   // pre-swizzled global col
    const unsigned short* g = src + (size_t)(row0 + r) * ld + k0 + kc;
    unsigned short* lb = lds + ((it * 256 + w * 64) << 3);  // wave-uniform
    __builtin_amdgcn_global_load_lds((const __attribute__((address_space(1))) void*)g,
                                     (__attribute__((address_space(3))) void*)lb,
                                     16, 0, 0);
  }
}

// compact-path staging: centered support from fp32 (swizzled ds_write)
__device__ inline void stage_sup_f32(const float* __restrict__ sup,
                                     const float* __restrict__ mean,
                                     int row0, int k0, unsigned short* lds) {
  const int tid = threadIdx.x;
#pragma unroll
  for (int it = 0; it < 4; ++it) {
    const int ci = it * 256 + tid;
    const int r = ci >> 3, kc = (ci & 7) << 3;
    const int c = row0 + r;
    const int k = k0 + kc;
    const int b = k >> 10, sp = k & 1023;
    const float4* g = (const float4*)(sup + ((size_t)b * CCH + c) * DSP + sp);
    const float4 v0 = g[0], v1 = g[1];
    const float m = mean[c];
    union { unsigned short h[8]; int4 q; } pk;
    pk.h[0] = f2bf(v0.x - m); pk.h[1] = f2bf(v0.y - m);
    pk.h[2] = f2bf(v0.z - m); pk.h[3] = f2bf(v0.w - m);
    pk.h[4] = f2bf(v1.x - m); pk.h[5] = f2bf(v1.y - m);
    pk.h[6] = f2bf(v1.z - m); pk.h[7] = f2bf(v1.w - m);
    *(int4*)(lds + (size_t)(r * 8 + ((ci & 7) ^ (r & 7))) * 8) = pk.q;
  }
}

// compact-path staging: normalized query from fp32 (swizzled ds_write)
__device__ inline void stage_q_f32(const float* __restrict__ qn,
                                   const float* __restrict__ qfacn,
                                   int row0, int k0, unsigned short* lds) {
  const int tid = threadIdx.x;
#pragma unroll
  for (int it = 0; it < 4; ++it) {
    const int ci = it * 256 + tid;
    const int r = ci >> 3, kc = (ci & 7) << 3;
    const int c = row0 + r;
    const float4* g = (const float4*)(qn + (size_t)c * DSP + k0 + kc);
    const float4 v0 = g[0], v1 = g[1];
    const float f = qfacn[c];
    union { unsigned short h[8]; int4 q; } pk;
    pk.h[0] = f2bf(v0.x * f); pk.h[1] = f2bf(v0.y * f);
    pk.h[2] = f2bf(v0.z * f); pk.h[3] = f2bf(v0.w * f);
    pk.h[4] = f2bf(v1.x * f); pk.h[5] = f2bf(v1.y * f);
    pk.h[6] = f2bf(v1.z * f); pk.h[7] = f2bf(v1.w * f);
    *(int4*)(lds + (size_t)(r * 8 + ((ci & 7) ^ (r & 7))) * 8) = pk.q;
  }
}

// one BK=64 compute step: 32 MFMAs per wave on 64x64 out sub-tile (swizzled read)
__device__ inline void compute_step(const unsigned short* lA, const unsigned short* lB,
                                    int wr, int wc, int lr, int kg, f32x4 acc[4][4]) {
  const int sc = (lr & 7) << 3;   // row&7 is lr&7 for every fragment row
#pragma unroll
  for (int kk = 0; kk < 64; kk += 32) {
    const int col = (kk + kg) ^ sc;
    bf16x8 a[4], b[4];
#pragma unroll
    for (int i = 0; i < 4; ++i)
      a[i] = *(const bf16x8*)(const void*)(lA + (wr + i * 16 + lr) * 64 + col);
#pragma unroll
    for (int j = 0; j < 4; ++j)
      b[j] = *(const bf16x8*)(const void*)(lB + (wc + j * 16 + lr) * 64 + col);
#pragma unroll
    for (int i = 0; i < 4; ++i)
#pragma unroll
      for (int j = 0; j < 4; ++j)
        acc[i][j] = __builtin_amdgcn_mfma_f32_16x16x32_bf16(a[i], b[j], acc[i][j], 0, 0, 0);
  }
}

__device__ inline void decode_tile(int t, int& ti, int& tj) {
  int rem = t; ti = 0;
  while (rem >= 8 - ti) { rem -= 8 - ti; ++ti; }
  tj = ti + rem;
}

// ---------------- cov = centered @ centered^T / (N-1+eps), upper tiles only ----------------
template <bool F32>
__global__ __launch_bounds__(256) void cov_kernel(
    const unsigned short* __restrict__ Sb, const float* __restrict__ sup,
    const float* __restrict__ mean, float* __restrict__ cov) {
  __shared__ unsigned short lA[128 * 64];
  __shared__ unsigned short lB[128 * 64];
  int ti, tj; decode_tile(blockIdx.x, ti, tj);
  const int ks = blockIdx.y;
  const int tid = threadIdx.x, l = tid & 63, w = tid >> 6;
  const int wr = (w >> 1) * 64, wc = (w & 1) * 64, lr = l & 15, kg = (l >> 4) * 8;
  f32x4 acc[4][4];
#pragma unroll
  for (int i = 0; i < 4; ++i)
#pragma unroll
    for (int j = 0; j < 4; ++j) acc[i][j] = 0.f;

  for (int kt = 0; kt < NK_COV; ++kt) {
    const int k0 = ks * (NSUP / KSLICES) + kt * 64;
    if (F32) {
      stage_sup_f32(sup, mean, ti * 128, k0, lA);
      stage_sup_f32(sup, mean, tj * 128, k0, lB);
    } else {
      stage_glds(Sb, NSUP, ti * 128, k0, lA);
      stage_glds(Sb, NSUP, tj * 128, k0, lB);
    }
    __syncthreads();
    compute_step(lA, lB, wr, wc, lr, kg, acc);
    __syncthreads();
  }
  const float scale = 1.0f / (25599.0f + 1e-8f);
  const int rbase = ti * 128 + wr + (l >> 4) * 4;
  const int cbase = tj * 128 + wc + (l & 15);
#pragma unroll
  for (int i = 0; i < 4; ++i)
#pragma unroll
    for (int j = 0; j < 4; ++j)
#pragma unroll
      for (int r = 0; r < 4; ++r)
        atomicAdd(&cov[(size_t)(rbase + i * 16 + r) * CCH + cbase + j * 16],
                  acc[i][j][r] * scale);
}

// ---------------- per-query Gram GEMM fused with cov Frobenius product ----------------
// 1-D grid 2304 = 8 xcd * 8 n-per-xcd * 36 tile-pairs: same-n blocks share an XCD's L2.
template <bool F32>
__global__ __launch_bounds__(256) void gram_kernel(
    const unsigned short* __restrict__ Qb, const float* __restrict__ q,
    const float* __restrict__ qfac, const float* __restrict__ cov,
    float* __restrict__ out) {
  __shared__ unsigned short lA[128 * 64];
  __shared__ unsigned short lB[128 * 64];
  const int wg = blockIdx.x;
  const int xcd = wg & 7, slot = wg >> 3;       // slot 0..287
  const int n = xcd * 8 + slot / 36;
  int ti, tj; decode_tile(slot % 36, ti, tj);
  const int tid = threadIdx.x, l = tid & 63, w = tid >> 6;
  const int wr = (w >> 1) * 64, wc = (w & 1) * 64, lr = l & 15, kg = (l >> 4) * 8;
  f32x4 acc[4][4];
#pragma unroll
  for (int i = 0; i < 4; ++i)
#pragma unroll
    for (int j = 0; j < 4; ++j) acc[i][j] = 0.f;

  const unsigned short* Qn = Qb + (size_t)n * CCH * DSP;
  const float* qn = q + (size_t)n * CCH * DSP;
  const float* qfacn = qfac + (size_t)n * CCH;

  for (int kt = 0; kt < 16; ++kt) {
    const int k0 = kt * 64;
    if (F32) {
      stage_q_f32(qn, qfacn, ti * 128, k0, lA);
      stage_q_f32(qn, qfacn, tj * 128, k0, lB);
    } else {
      stage_glds(Qn, DSP, ti * 128, k0, lA);
      stage_glds(Qn, DSP, tj * 128, k0, lB);
    }
    __syncthreads();
    compute_step(lA, lB, wr, wc, lr, kg, acc);
    __syncthreads();
  }
  float s = 0.f;
  const int rbase = ti * 128 + wr + (l >> 4) * 4;
  const int cbase = tj * 128 + wc + (l & 15);
#pragma unroll
  for (int i = 0; i < 4; ++i)
#pragma unroll
    for (int j = 0; j < 4; ++j)
#pragma unroll
      for (int r = 0; r < 4; ++r)
        s += acc[i][j][r] * cov[(size_t)(rbase + i * 16 + r) * CCH + cbase + j * 16];
  if (ti != tj) s *= 2.0f;
  s *= (1.0f / 1024.0f);
#pragma unroll
  for (int off = 32; off > 0; off >>= 1) s += __shfl_xor(s, off);
  if (l == 0) atomicAdd(&out[n], s);
}

// ---------------- launch ----------------
extern "C" void kernel_launch(void* const* d_in, const int* in_sizes, int n_in,
                              void* d_out, int out_size, void* d_ws, size_t ws_size,
                              hipStream_t stream) {
  const float* q = (const float*)d_in[0];
  const float* sup = (const float*)d_in[1];
  float* out = (float*)d_out;

  char* ws = (char*)d_ws;
  float* mean = (float*)ws;                                  // 4 KB
  float* qfac = (float*)(ws + (4 << 10));                    // 256 KB
  float* cov  = (float*)(ws + (4 << 10) + (256 << 10));      // 4 MB
  unsigned short* Sb = (unsigned short*)(ws + (4 << 10) + (256 << 10) + (4 << 20));
  unsigned short* Qb = Sb + (size_t)CCH * NSUP;
  const size_t need_fat = (size_t)(4 << 10) + (256 << 10) + (4 << 20) +
                          (size_t)CCH * NSUP * 2 + (size_t)NQ * CCH * DSP * 2;
  const bool fat = ws_size >= need_fat;

  hipMemsetAsync(out, 0, (size_t)out_size * sizeof(float), stream);
  hipMemsetAsync(cov, 0, (size_t)CCH * CCH * sizeof(float), stream);

  mean_center_kernel<<<CCH, 256, 0, stream>>>(sup, mean, Sb, fat ? 1 : 0);
  qnorm_kernel<<<NQ * CCH / 4, 256, 0, stream>>>(q, qfac, Qb, fat ? 1 : 0);

  if (fat) {
    cov_kernel<false><<<dim3(36, KSLICES), 256, 0, stream>>>(Sb, sup, mean, cov);
    gram_kernel<false><<<dim3(8 * 8 * 36), 256, 0, stream>>>(Qb, q, qfac, cov, out);
  } else {
    cov_kernel<true><<<dim3(36, KSLICES), 256, 0, stream>>>(Sb, sup, mean, cov);
    gram_kernel<true><<<dim3(8 * 8 * 36), 256, 0, stream>>>(Qb, q, qfac, cov, out);
  }
}

// Round 3
// 332.726 us; speedup vs baseline: 1.1950x; 1.0254x over previous
//
#include <hip/hip_runtime.h>

#define NQ   64
#define CCH  1024
#define DSP  1024      // 32*32 spatial
#define NSUP 25600     // 25*32*32
#define KSLICES 8
#define NK_COV 50      // 25600/8/64

typedef __attribute__((ext_vector_type(4))) float f32x4;
typedef __attribute__((ext_vector_type(8))) __bf16 bf16x8;

__device__ inline unsigned short f2bf(float x) {
  unsigned u = __builtin_bit_cast(unsigned, x);
  u += 0x7fffu + ((u >> 16) & 1u);
  return (unsigned short)(u >> 16);
}

// ---------------- zero kernel (replaces pathological runtime fill) ----------------
// cov is 1024*1024 floats = 262144 float4 -> 1024 blocks x 256 threads.
// out is 64 floats = 16 float4, zeroed by the first 16 threads.
__global__ __launch_bounds__(256) void zero_kernel(float4* __restrict__ cov4,
                                                   float4* __restrict__ out4) {
  const int i = blockIdx.x * 256 + threadIdx.x;
  cov4[i] = make_float4(0.f, 0.f, 0.f, 0.f);
  if (i < 16) out4[i] = make_float4(0.f, 0.f, 0.f, 0.f);
}

// ---------------- prep kernels ----------------

// one block per channel c: mean over 25600 support elems, then (optionally)
// write centered bf16 row Sb[c][k], k = b*1024 + s
__global__ __launch_bounds__(256) void mean_center_kernel(
    const float* __restrict__ sup, float* __restrict__ mean,
    unsigned short* __restrict__ Sb, int write_sb) {
  const int c = blockIdx.x;
  const int tid = threadIdx.x;
  float s = 0.f;
  for (int qd = tid; qd < 6400; qd += 256) {
    const int b = qd >> 8, s4 = (qd & 255) << 2;
    const float4 v = *(const float4*)(sup + ((size_t)b * CCH + c) * DSP + s4);
    s += v.x + v.y + v.z + v.w;
  }
  __shared__ float red[256];
  red[tid] = s;
  __syncthreads();
  for (int st = 128; st > 0; st >>= 1) {
    if (tid < st) red[tid] += red[tid + st];
    __syncthreads();
  }
  const float m = red[0] * (1.0f / 25600.0f);
  if (tid == 0) mean[c] = m;
  if (write_sb) {
    for (int qd = tid; qd < 6400; qd += 256) {
      const int b = qd >> 8, s4 = (qd & 255) << 2;
      const float4 v = *(const float4*)(sup + ((size_t)b * CCH + c) * DSP + s4);
      ushort4 o;
      o.x = f2bf(v.x - m); o.y = f2bf(v.y - m);
      o.z = f2bf(v.z - m); o.w = f2bf(v.w - m);
      *(ushort4*)(Sb + (size_t)c * NSUP + b * DSP + s4) = o;
    }
  }
}

// one wave per (n,c) row of 1024: L2 norm factor, optionally write bf16 Qb
__global__ __launch_bounds__(256) void qnorm_kernel(
    const float* __restrict__ q, float* __restrict__ qfac,
    unsigned short* __restrict__ Qb, int write_qb) {
  const int row = blockIdx.x * 4 + (threadIdx.x >> 6);
  const int l = threadIdx.x & 63;
  const float4* src = (const float4*)(q + (size_t)row * DSP);
  float4 v[4];
  float ss = 0.f;
#pragma unroll
  for (int i = 0; i < 4; ++i) {
    v[i] = src[l + 64 * i];
    ss += v[i].x * v[i].x + v[i].y * v[i].y + v[i].z * v[i].z + v[i].w * v[i].w;
  }
#pragma unroll
  for (int off = 32; off > 0; off >>= 1) ss += __shfl_xor(ss, off);
  const float f = 1.0f / (sqrtf(ss) + 1e-8f);
  if (l == 0) qfac[row] = f;
  if (write_qb) {
#pragma unroll
    for (int i = 0; i < 4; ++i) {
      ushort4 o;
      o.x = f2bf(v[i].x * f); o.y = f2bf(v[i].y * f);
      o.z = f2bf(v[i].z * f); o.w = f2bf(v[i].w * f);
      *(ushort4*)(Qb + (size_t)row * DSP + (size_t)(l + 64 * i) * 4) = o;
    }
  }
}

// ---------------- GEMM building blocks ----------------
// LDS layout: [128 rows][64 cols] bf16, XOR-swizzled: LDS[row][c ^ ((row&7)<<3)]
// holds logical (row, c). global_load_lds writes linearly, so the SOURCE column
// is pre-swizzled (rule #21: both-sides-or-neither).

// stage a 128x64 bf16 tile (row-major, ld elems) into swizzled LDS
__device__ inline void stage_glds(const unsigned short* __restrict__ src, int ld,
                                  int row0, int k0, unsigned short* lds) {
  const int tid = threadIdx.x;
  const int w = tid >> 6;
#pragma unroll
  for (int it = 0; it < 4; ++it) {
    const int ci = it * 256 + tid;          // chunk 0..1023 (16B each)
    const int r = ci >> 3;
    const int kc = ((ci & 7) ^ (r & 7)) << 3;   // pre-swizzled global col
    const unsigned short* g = src + (size_t)(row0 + r) * ld + k0 + kc;
    unsigned short* lb = lds + ((it * 256 + w * 64) << 3);  // wave-uniform
    __builtin_amdgcn_global_load_lds((const __attribute__((address_space(1))) void*)g,
                                     (__attribute__((address_space(3))) void*)lb,
                                     16, 0, 0);
  }
}

// compact-path staging: centered support from fp32 (swizzled ds_write)
__device__ inline void stage_sup_f32(const float* __restrict__ sup,
                                     const float* __restrict__ mean,
                                     int row0, int k0, unsigned short* lds) {
  const int tid = threadIdx.x;
#pragma unroll
  for (int it = 0; it < 4; ++it) {
    const int ci = it * 256 + tid;
    const int r = ci >> 3, kc = (ci & 7) << 3;
    const int c = row0 + r;
    const int k = k0 + kc;
    const int b = k >> 10, sp = k & 1023;
    const float4* g = (const float4*)(sup + ((size_t)b * CCH + c) * DSP + sp);
    const float4 v0 = g[0], v1 = g[1];
    const float m = mean[c];
    union { unsigned short h[8]; int4 q; } pk;
    pk.h[0] = f2bf(v0.x - m); pk.h[1] = f2bf(v0.y - m);
    pk.h[2] = f2bf(v0.z - m); pk.h[3] = f2bf(v0.w - m);
    pk.h[4] = f2bf(v1.x - m); pk.h[5] = f2bf(v1.y - m);
    pk.h[6] = f2bf(v1.z - m); pk.h[7] = f2bf(v1.w - m);
    *(int4*)(lds + (size_t)(r * 8 + ((ci & 7) ^ (r & 7))) * 8) = pk.q;
  }
}

// compact-path staging: normalized query from fp32 (swizzled ds_write)
__device__ inline void stage_q_f32(const float* __restrict__ qn,
                                   const float* __restrict__ qfacn,
                                   int row0, int k0, unsigned short* lds) {
  const int tid = threadIdx.x;
#pragma unroll
  for (int it = 0; it < 4; ++it) {
    const int ci = it * 256 + tid;
    const int r = ci >> 3, kc = (ci & 7) << 3;
    const int c = row0 + r;
    const float4* g = (const float4*)(qn + (size_t)c * DSP + k0 + kc);
    const float4 v0 = g[0], v1 = g[1];
    const float f = qfacn[c];
    union { unsigned short h[8]; int4 q; } pk;
    pk.h[0] = f2bf(v0.x * f); pk.h[1] = f2bf(v0.y * f);
    pk.h[2] = f2bf(v0.z * f); pk.h[3] = f2bf(v0.w * f);
    pk.h[4] = f2bf(v1.x * f); pk.h[5] = f2bf(v1.y * f);
    pk.h[6] = f2bf(v1.z * f); pk.h[7] = f2bf(v1.w * f);
    *(int4*)(lds + (size_t)(r * 8 + ((ci & 7) ^ (r & 7))) * 8) = pk.q;
  }
}

// one BK=64 compute step: 32 MFMAs per wave on 64x64 out sub-tile (swizzled read)
__device__ inline void compute_step(const unsigned short* lA, const unsigned short* lB,
                                    int wr, int wc, int lr, int kg, f32x4 acc[4][4]) {
  const int sc = (lr & 7) << 3;   // row&7 is lr&7 for every fragment row
#pragma unroll
  for (int kk = 0; kk < 64; kk += 32) {
    const int col = (kk + kg) ^ sc;
    bf16x8 a[4], b[4];
#pragma unroll
    for (int i = 0; i < 4; ++i)
      a[i] = *(const bf16x8*)(const void*)(lA + (wr + i * 16 + lr) * 64 + col);
#pragma unroll
    for (int j = 0; j < 4; ++j)
      b[j] = *(const bf16x8*)(const void*)(lB + (wc + j * 16 + lr) * 64 + col);
#pragma unroll
    for (int i = 0; i < 4; ++i)
#pragma unroll
      for (int j = 0; j < 4; ++j)
        acc[i][j] = __builtin_amdgcn_mfma_f32_16x16x32_bf16(a[i], b[j], acc[i][j], 0, 0, 0);
  }
}

__device__ inline void decode_tile(int t, int& ti, int& tj) {
  int rem = t; ti = 0;
  while (rem >= 8 - ti) { rem -= 8 - ti; ++ti; }
  tj = ti + rem;
}

// ---------------- cov = centered @ centered^T / (N-1+eps), upper tiles only ----------------
template <bool F32>
__global__ __launch_bounds__(256) void cov_kernel(
    const unsigned short* __restrict__ Sb, const float* __restrict__ sup,
    const float* __restrict__ mean, float* __restrict__ cov) {
  __shared__ unsigned short lA[128 * 64];
  __shared__ unsigned short lB[128 * 64];
  int ti, tj; decode_tile(blockIdx.x, ti, tj);
  const int ks = blockIdx.y;
  const int tid = threadIdx.x, l = tid & 63, w = tid >> 6;
  const int wr = (w >> 1) * 64, wc = (w & 1) * 64, lr = l & 15, kg = (l >> 4) * 8;
  f32x4 acc[4][4];
#pragma unroll
  for (int i = 0; i < 4; ++i)
#pragma unroll
    for (int j = 0; j < 4; ++j) acc[i][j] = 0.f;

  for (int kt = 0; kt < NK_COV; ++kt) {
    const int k0 = ks * (NSUP / KSLICES) + kt * 64;
    if (F32) {
      stage_sup_f32(sup, mean, ti * 128, k0, lA);
      stage_sup_f32(sup, mean, tj * 128, k0, lB);
    } else {
      stage_glds(Sb, NSUP, ti * 128, k0, lA);
      stage_glds(Sb, NSUP, tj * 128, k0, lB);
    }
    __syncthreads();
    compute_step(lA, lB, wr, wc, lr, kg, acc);
    __syncthreads();
  }
  const float scale = 1.0f / (25599.0f + 1e-8f);
  const int rbase = ti * 128 + wr + (l >> 4) * 4;
  const int cbase = tj * 128 + wc + (l & 15);
#pragma unroll
  for (int i = 0; i < 4; ++i)
#pragma unroll
    for (int j = 0; j < 4; ++j)
#pragma unroll
      for (int r = 0; r < 4; ++r)
        atomicAdd(&cov[(size_t)(rbase + i * 16 + r) * CCH + cbase + j * 16],
                  acc[i][j][r] * scale);
}

// ---------------- per-query Gram GEMM fused with cov Frobenius product ----------------
// 1-D grid 2304 = 8 xcd * 8 n-per-xcd * 36 tile-pairs: same-n blocks share an XCD's L2.
template <bool F32>
__global__ __launch_bounds__(256) void gram_kernel(
    const unsigned short* __restrict__ Qb, const float* __restrict__ q,
    const float* __restrict__ qfac, const float* __restrict__ cov,
    float* __restrict__ out) {
  __shared__ unsigned short lA[128 * 64];
  __shared__ unsigned short lB[128 * 64];
  const int wg = blockIdx.x;
  const int xcd = wg & 7, slot = wg >> 3;       // slot 0..287
  const int n = xcd * 8 + slot / 36;
  int ti, tj; decode_tile(slot % 36, ti, tj);
  const int tid = threadIdx.x, l = tid & 63, w = tid >> 6;
  const int wr = (w >> 1) * 64, wc = (w & 1) * 64, lr = l & 15, kg = (l >> 4) * 8;
  f32x4 acc[4][4];
#pragma unroll
  for (int i = 0; i < 4; ++i)
#pragma unroll
    for (int j = 0; j < 4; ++j) acc[i][j] = 0.f;

  const unsigned short* Qn = Qb + (size_t)n * CCH * DSP;
  const float* qn = q + (size_t)n * CCH * DSP;
  const float* qfacn = qfac + (size_t)n * CCH;

  for (int kt = 0; kt < 16; ++kt) {
    const int k0 = kt * 64;
    if (F32) {
      stage_q_f32(qn, qfacn, ti * 128, k0, lA);
      stage_q_f32(qn, qfacn, tj * 128, k0, lB);
    } else {
      stage_glds(Qn, DSP, ti * 128, k0, lA);
      stage_glds(Qn, DSP, tj * 128, k0, lB);
    }
    __syncthreads();
    compute_step(lA, lB, wr, wc, lr, kg, acc);
    __syncthreads();
  }
  float s = 0.f;
  const int rbase = ti * 128 + wr + (l >> 4) * 4;
  const int cbase = tj * 128 + wc + (l & 15);
#pragma unroll
  for (int i = 0; i < 4; ++i)
#pragma unroll
    for (int j = 0; j < 4; ++j)
#pragma unroll
      for (int r = 0; r < 4; ++r)
        s += acc[i][j][r] * cov[(size_t)(rbase + i * 16 + r) * CCH + cbase + j * 16];
  if (ti != tj) s *= 2.0f;
  s *= (1.0f / 1024.0f);
#pragma unroll
  for (int off = 32; off > 0; off >>= 1) s += __shfl_xor(s, off);
  if (l == 0) atomicAdd(&out[n], s);
}

// ---------------- launch ----------------
extern "C" void kernel_launch(void* const* d_in, const int* in_sizes, int n_in,
                              void* d_out, int out_size, void* d_ws, size_t ws_size,
                              hipStream_t stream) {
  const float* q = (const float*)d_in[0];
  const float* sup = (const float*)d_in[1];
  float* out = (float*)d_out;

  char* ws = (char*)d_ws;
  float* mean = (float*)ws;                                  // 4 KB
  float* qfac = (float*)(ws + (4 << 10));                    // 256 KB
  float* cov  = (float*)(ws + (4 << 10) + (256 << 10));      // 4 MB
  unsigned short* Sb = (unsigned short*)(ws + (4 << 10) + (256 << 10) + (4 << 20));
  unsigned short* Qb = Sb + (size_t)CCH * NSUP;
  const size_t need_fat = (size_t)(4 << 10) + (256 << 10) + (4 << 20) +
                          (size_t)CCH * NSUP * 2 + (size_t)NQ * CCH * DSP * 2;
  const bool fat = ws_size >= need_fat;

  zero_kernel<<<1024, 256, 0, stream>>>((float4*)cov, (float4*)out);

  mean_center_kernel<<<CCH, 256, 0, stream>>>(sup, mean, Sb, fat ? 1 : 0);
  qnorm_kernel<<<NQ * CCH / 4, 256, 0, stream>>>(q, qfac, Qb, fat ? 1 : 0);

  if (fat) {
    cov_kernel<false><<<dim3(36, KSLICES), 256, 0, stream>>>(Sb, sup, mean, cov);
    gram_kernel<false><<<dim3(8 * 8 * 36), 256, 0, stream>>>(Qb, q, qfac, cov, out);
  } else {
    cov_kernel<true><<<dim3(36, KSLICES), 256, 0, stream>>>(Sb, sup, mean, cov);
    gram_kernel<true><<<dim3(8 * 8 * 36), 256, 0, stream>>>(Qb, q, qfac, cov, out);
  }
}

// Round 4
// 306.293 us; speedup vs baseline: 1.2981x; 1.0863x over previous
//
#include <hip/hip_runtime.h>

#define NQ   64
#define CCH  1024
#define DSP  1024      // 32*32 spatial
#define NSUP 25600     // 25*32*32
#define KSLICES 8
#define NK_COV 50      // 25600/8/64

typedef __attribute__((ext_vector_type(4))) float f32x4;
typedef __attribute__((ext_vector_type(8))) __bf16 bf16x8;

__device__ inline unsigned short f2bf(float x) {
  unsigned u = __builtin_bit_cast(unsigned, x);
  u += 0x7fffu + ((u >> 16) & 1u);
  return (unsigned short)(u >> 16);
}

// ---------------- zero kernel ----------------
__global__ __launch_bounds__(256) void zero_kernel(float4* __restrict__ cov4,
                                                   float4* __restrict__ out4) {
  const int i = blockIdx.x * 256 + threadIdx.x;
  cov4[i] = make_float4(0.f, 0.f, 0.f, 0.f);
  if (i < 16) out4[i] = make_float4(0.f, 0.f, 0.f, 0.f);
}

// ---------------- prep kernels ----------------

// one block per channel c: mean over 25600 support elems, then (optionally)
// write centered bf16 row Sb[c][k], k = b*1024 + s
__global__ __launch_bounds__(256) void mean_center_kernel(
    const float* __restrict__ sup, float* __restrict__ mean,
    unsigned short* __restrict__ Sb, int write_sb) {
  const int c = blockIdx.x;
  const int tid = threadIdx.x;
  float s = 0.f;
  for (int qd = tid; qd < 6400; qd += 256) {
    const int b = qd >> 8, s4 = (qd & 255) << 2;
    const float4 v = *(const float4*)(sup + ((size_t)b * CCH + c) * DSP + s4);
    s += v.x + v.y + v.z + v.w;
  }
  __shared__ float red[256];
  red[tid] = s;
  __syncthreads();
  for (int st = 128; st > 0; st >>= 1) {
    if (tid < st) red[tid] += red[tid + st];
    __syncthreads();
  }
  const float m = red[0] * (1.0f / 25600.0f);
  if (tid == 0) mean[c] = m;
  if (write_sb) {
    for (int qd = tid; qd < 6400; qd += 256) {
      const int b = qd >> 8, s4 = (qd & 255) << 2;
      const float4 v = *(const float4*)(sup + ((size_t)b * CCH + c) * DSP + s4);
      ushort4 o;
      o.x = f2bf(v.x - m); o.y = f2bf(v.y - m);
      o.z = f2bf(v.z - m); o.w = f2bf(v.w - m);
      *(ushort4*)(Sb + (size_t)c * NSUP + b * DSP + s4) = o;
    }
  }
}

// one wave per (n,c) row of 1024: L2 norm factor, optionally write bf16 Qb
__global__ __launch_bounds__(256) void qnorm_kernel(
    const float* __restrict__ q, float* __restrict__ qfac,
    unsigned short* __restrict__ Qb, int write_qb) {
  const int row = blockIdx.x * 4 + (threadIdx.x >> 6);
  const int l = threadIdx.x & 63;
  const float4* src = (const float4*)(q + (size_t)row * DSP);
  float4 v[4];
  float ss = 0.f;
#pragma unroll
  for (int i = 0; i < 4; ++i) {
    v[i] = src[l + 64 * i];
    ss += v[i].x * v[i].x + v[i].y * v[i].y + v[i].z * v[i].z + v[i].w * v[i].w;
  }
#pragma unroll
  for (int off = 32; off > 0; off >>= 1) ss += __shfl_xor(ss, off);
  const float f = 1.0f / (sqrtf(ss) + 1e-8f);
  if (l == 0) qfac[row] = f;
  if (write_qb) {
#pragma unroll
    for (int i = 0; i < 4; ++i) {
      ushort4 o;
      o.x = f2bf(v[i].x * f); o.y = f2bf(v[i].y * f);
      o.z = f2bf(v[i].z * f); o.w = f2bf(v[i].w * f);
      *(ushort4*)(Qb + (size_t)row * DSP + (size_t)(l + 64 * i) * 4) = o;
    }
  }
}

// ---------------- GEMM building blocks ----------------
// LDS layout: [128 rows][64 cols] bf16, XOR-swizzled: LDS[row][c ^ ((row&7)<<3)]
// holds logical (row, c). global_load_lds writes linearly, so the SOURCE column
// is pre-swizzled (rule #21: both-sides-or-neither).

// stage a 128x64 bf16 tile (row-major, ld elems) into swizzled LDS
__device__ inline void stage_glds(const unsigned short* __restrict__ src, int ld,
                                  int row0, int k0, unsigned short* lds) {
  const int tid = threadIdx.x;
  const int w = tid >> 6;
#pragma unroll
  for (int it = 0; it < 4; ++it) {
    const int ci = it * 256 + tid;          // chunk 0..1023 (16B each)
    const int r = ci >> 3;
    const int kc = ((ci & 7) ^ (r & 7)) << 3;   // pre-swizzled global col
    const unsigned short* g = src + (size_t)(row0 + r) * ld + k0 + kc;
    unsigned short* lb = lds + ((it * 256 + w * 64) << 3);  // wave-uniform
    __builtin_amdgcn_global_load_lds((const __attribute__((address_space(1))) void*)g,
                                     (__attribute__((address_space(3))) void*)lb,
                                     16, 0, 0);
  }
}

// compact-path staging: centered support from fp32 (swizzled ds_write)
__device__ inline void stage_sup_f32(const float* __restrict__ sup,
                                     const float* __restrict__ mean,
                                     int row0, int k0, unsigned short* lds) {
  const int tid = threadIdx.x;
#pragma unroll
  for (int it = 0; it < 4; ++it) {
    const int ci = it * 256 + tid;
    const int r = ci >> 3, kc = (ci & 7) << 3;
    const int c = row0 + r;
    const int k = k0 + kc;
    const int b = k >> 10, sp = k & 1023;
    const float4* g = (const float4*)(sup + ((size_t)b * CCH + c) * DSP + sp);
    const float4 v0 = g[0], v1 = g[1];
    const float m = mean[c];
    union { unsigned short h[8]; int4 q; } pk;
    pk.h[0] = f2bf(v0.x - m); pk.h[1] = f2bf(v0.y - m);
    pk.h[2] = f2bf(v0.z - m); pk.h[3] = f2bf(v0.w - m);
    pk.h[4] = f2bf(v1.x - m); pk.h[5] = f2bf(v1.y - m);
    pk.h[6] = f2bf(v1.z - m); pk.h[7] = f2bf(v1.w - m);
    *(int4*)(lds + (size_t)(r * 8 + ((ci & 7) ^ (r & 7))) * 8) = pk.q;
  }
}

// compact-path staging: normalized query from fp32 (swizzled ds_write)
__device__ inline void stage_q_f32(const float* __restrict__ qn,
                                   const float* __restrict__ qfacn,
                                   int row0, int k0, unsigned short* lds) {
  const int tid = threadIdx.x;
#pragma unroll
  for (int it = 0; it < 4; ++it) {
    const int ci = it * 256 + tid;
    const int r = ci >> 3, kc = (ci & 7) << 3;
    const int c = row0 + r;
    const float4* g = (const float4*)(qn + (size_t)c * DSP + k0 + kc);
    const float4 v0 = g[0], v1 = g[1];
    const float f = qfacn[c];
    union { unsigned short h[8]; int4 q; } pk;
    pk.h[0] = f2bf(v0.x * f); pk.h[1] = f2bf(v0.y * f);
    pk.h[2] = f2bf(v0.z * f); pk.h[3] = f2bf(v0.w * f);
    pk.h[4] = f2bf(v1.x * f); pk.h[5] = f2bf(v1.y * f);
    pk.h[6] = f2bf(v1.z * f); pk.h[7] = f2bf(v1.w * f);
    *(int4*)(lds + (size_t)(r * 8 + ((ci & 7) ^ (r & 7))) * 8) = pk.q;
  }
}

// one BK=64 compute step: 32 MFMAs per wave on 64x64 out sub-tile (swizzled read)
__device__ inline void compute_step(const unsigned short* lA, const unsigned short* lB,
                                    int wr, int wc, int lr, int kg, f32x4 acc[4][4]) {
  const int sc = (lr & 7) << 3;   // row&7 is lr&7 for every fragment row
  __builtin_amdgcn_s_setprio(1);
#pragma unroll
  for (int kk = 0; kk < 64; kk += 32) {
    const int col = (kk + kg) ^ sc;
    bf16x8 a[4], b[4];
#pragma unroll
    for (int i = 0; i < 4; ++i)
      a[i] = *(const bf16x8*)(const void*)(lA + (wr + i * 16 + lr) * 64 + col);
#pragma unroll
    for (int j = 0; j < 4; ++j)
      b[j] = *(const bf16x8*)(const void*)(lB + (wc + j * 16 + lr) * 64 + col);
#pragma unroll
    for (int i = 0; i < 4; ++i)
#pragma unroll
      for (int j = 0; j < 4; ++j)
        acc[i][j] = __builtin_amdgcn_mfma_f32_16x16x32_bf16(a[i], b[j], acc[i][j], 0, 0, 0);
  }
  __builtin_amdgcn_s_setprio(0);
}

__device__ inline void decode_tile(int t, int& ti, int& tj) {
  int rem = t; ti = 0;
  while (rem >= 8 - ti) { rem -= 8 - ti; ++ti; }
  tj = ti + rem;
}

// ---------------- cov = centered @ centered^T / (N-1+eps), upper tiles only ----------------
// 2-phase double-buffered K-loop: stage(t+1) issued BEFORE compute(t); single
// barrier per step (compiler's vmcnt/lgkmcnt drain before s_barrier covers the
// cross-wave LDS visibility). Diag tiles stage only A and read B from A.
template <bool F32>
__global__ __launch_bounds__(256) void cov_kernel(
    const unsigned short* __restrict__ Sb, const float* __restrict__ sup,
    const float* __restrict__ mean, float* __restrict__ cov) {
  __shared__ unsigned short lA[2][128 * 64];
  __shared__ unsigned short lB[2][128 * 64];
  int ti, tj; decode_tile(blockIdx.x, ti, tj);
  const int ks = blockIdx.y;
  const bool diag = (ti == tj);
  const int tid = threadIdx.x, l = tid & 63, w = tid >> 6;
  const int wr = (w >> 1) * 64, wc = (w & 1) * 64, lr = l & 15, kg = (l >> 4) * 8;
  f32x4 acc[4][4];
#pragma unroll
  for (int i = 0; i < 4; ++i)
#pragma unroll
    for (int j = 0; j < 4; ++j) acc[i][j] = 0.f;

  const int kbase = ks * (NSUP / KSLICES);

  // prologue: stage tile 0 into buffer 0
  if (F32) {
    stage_sup_f32(sup, mean, ti * 128, kbase, lA[0]);
    if (!diag) stage_sup_f32(sup, mean, tj * 128, kbase, lB[0]);
  } else {
    stage_glds(Sb, NSUP, ti * 128, kbase, lA[0]);
    if (!diag) stage_glds(Sb, NSUP, tj * 128, kbase, lB[0]);
  }
  __syncthreads();

  int cur = 0;
  for (int kt = 0; kt < NK_COV; ++kt) {
    if (kt + 1 < NK_COV) {
      const int k1 = kbase + (kt + 1) * 64;
      if (F32) {
        stage_sup_f32(sup, mean, ti * 128, k1, lA[cur ^ 1]);
        if (!diag) stage_sup_f32(sup, mean, tj * 128, k1, lB[cur ^ 1]);
      } else {
        stage_glds(Sb, NSUP, ti * 128, k1, lA[cur ^ 1]);
        if (!diag) stage_glds(Sb, NSUP, tj * 128, k1, lB[cur ^ 1]);
      }
    }
    compute_step(lA[cur], diag ? lA[cur] : lB[cur], wr, wc, lr, kg, acc);
    __syncthreads();
    cur ^= 1;
  }

  const float scale = 1.0f / (25599.0f + 1e-8f);
  const int rbase = ti * 128 + wr + (l >> 4) * 4;
  const int cbase = tj * 128 + wc + (l & 15);
#pragma unroll
  for (int i = 0; i < 4; ++i)
#pragma unroll
    for (int j = 0; j < 4; ++j)
#pragma unroll
      for (int r = 0; r < 4; ++r)
        atomicAdd(&cov[(size_t)(rbase + i * 16 + r) * CCH + cbase + j * 16],
                  acc[i][j][r] * scale);
}

// ---------------- per-query Gram GEMM fused with cov Frobenius product ----------------
// 1-D grid 2304 = 8 xcd * 8 n-per-xcd * 36 tile-pairs: same-n blocks share an XCD's L2.
template <bool F32>
__global__ __launch_bounds__(256) void gram_kernel(
    const unsigned short* __restrict__ Qb, const float* __restrict__ q,
    const float* __restrict__ qfac, const float* __restrict__ cov,
    float* __restrict__ out) {
  __shared__ unsigned short lA[2][128 * 64];
  __shared__ unsigned short lB[2][128 * 64];
  const int wg = blockIdx.x;
  const int xcd = wg & 7, slot = wg >> 3;       // slot 0..287
  const int n = xcd * 8 + slot / 36;
  int ti, tj; decode_tile(slot % 36, ti, tj);
  const bool diag = (ti == tj);
  const int tid = threadIdx.x, l = tid & 63, w = tid >> 6;
  const int wr = (w >> 1) * 64, wc = (w & 1) * 64, lr = l & 15, kg = (l >> 4) * 8;
  f32x4 acc[4][4];
#pragma unroll
  for (int i = 0; i < 4; ++i)
#pragma unroll
    for (int j = 0; j < 4; ++j) acc[i][j] = 0.f;

  const unsigned short* Qn = Qb + (size_t)n * CCH * DSP;
  const float* qn = q + (size_t)n * CCH * DSP;
  const float* qfacn = qfac + (size_t)n * CCH;

  // prologue
  if (F32) {
    stage_q_f32(qn, qfacn, ti * 128, 0, lA[0]);
    if (!diag) stage_q_f32(qn, qfacn, tj * 128, 0, lB[0]);
  } else {
    stage_glds(Qn, DSP, ti * 128, 0, lA[0]);
    if (!diag) stage_glds(Qn, DSP, tj * 128, 0, lB[0]);
  }
  __syncthreads();

  int cur = 0;
  for (int kt = 0; kt < 16; ++kt) {
    if (kt + 1 < 16) {
      const int k1 = (kt + 1) * 64;
      if (F32) {
        stage_q_f32(qn, qfacn, ti * 128, k1, lA[cur ^ 1]);
        if (!diag) stage_q_f32(qn, qfacn, tj * 128, k1, lB[cur ^ 1]);
      } else {
        stage_glds(Qn, DSP, ti * 128, k1, lA[cur ^ 1]);
        if (!diag) stage_glds(Qn, DSP, tj * 128, k1, lB[cur ^ 1]);
      }
    }
    compute_step(lA[cur], diag ? lA[cur] : lB[cur], wr, wc, lr, kg, acc);
    __syncthreads();
    cur ^= 1;
  }

  float s = 0.f;
  const int rbase = ti * 128 + wr + (l >> 4) * 4;
  const int cbase = tj * 128 + wc + (l & 15);
#pragma unroll
  for (int i = 0; i < 4; ++i)
#pragma unroll
    for (int j = 0; j < 4; ++j)
#pragma unroll
      for (int r = 0; r < 4; ++r)
        s += acc[i][j][r] * cov[(size_t)(rbase + i * 16 + r) * CCH + cbase + j * 16];
  if (!diag) s *= 2.0f;
  s *= (1.0f / 1024.0f);
#pragma unroll
  for (int off = 32; off > 0; off >>= 1) s += __shfl_xor(s, off);
  if (l == 0) atomicAdd(&out[n], s);
}

// ---------------- launch ----------------
extern "C" void kernel_launch(void* const* d_in, const int* in_sizes, int n_in,
                              void* d_out, int out_size, void* d_ws, size_t ws_size,
                              hipStream_t stream) {
  const float* q = (const float*)d_in[0];
  const float* sup = (const float*)d_in[1];
  float* out = (float*)d_out;

  char* ws = (char*)d_ws;
  float* mean = (float*)ws;                                  // 4 KB
  float* qfac = (float*)(ws + (4 << 10));                    // 256 KB
  float* cov  = (float*)(ws + (4 << 10) + (256 << 10));      // 4 MB
  unsigned short* Sb = (unsigned short*)(ws + (4 << 10) + (256 << 10) + (4 << 20));
  unsigned short* Qb = Sb + (size_t)CCH * NSUP;
  const size_t need_fat = (size_t)(4 << 10) + (256 << 10) + (4 << 20) +
                          (size_t)CCH * NSUP * 2 + (size_t)NQ * CCH * DSP * 2;
  const bool fat = ws_size >= need_fat;

  zero_kernel<<<1024, 256, 0, stream>>>((float4*)cov, (float4*)out);

  mean_center_kernel<<<CCH, 256, 0, stream>>>(sup, mean, Sb, fat ? 1 : 0);
  qnorm_kernel<<<NQ * CCH / 4, 256, 0, stream>>>(q, qfac, Qb, fat ? 1 : 0);

  if (fat) {
    cov_kernel<false><<<dim3(36, KSLICES), 256, 0, stream>>>(Sb, sup, mean, cov);
    gram_kernel<false><<<dim3(8 * 8 * 36), 256, 0, stream>>>(Qb, q, qfac, cov, out);
  } else {
    cov_kernel<true><<<dim3(36, KSLICES), 256, 0, stream>>>(Sb, sup, mean, cov);
    gram_kernel<true><<<dim3(8 * 8 * 36), 256, 0, stream>>>(Qb, q, qfac, cov, out);
  }
}

// Round 5
// 303.625 us; speedup vs baseline: 1.3095x; 1.0088x over previous
//
#include <hip/hip_runtime.h>

#define NQ   64
#define CCH  1024
#define DSP  1024      // 32*32 spatial
#define NSUP 25600     // 25*32*32
#define KSLICES 8
#define NK_COV 50      // 25600/8/64

typedef __attribute__((ext_vector_type(4))) float f32x4;
typedef __attribute__((ext_vector_type(8))) __bf16 bf16x8;

#define WAITVM(N) asm volatile("s_waitcnt vmcnt(" #N ")" ::: "memory")
#define WAITLGKM0() asm volatile("s_waitcnt lgkmcnt(0)" ::: "memory")

__device__ inline unsigned short f2bf(float x) {
  unsigned u = __builtin_bit_cast(unsigned, x);
  u += 0x7fffu + ((u >> 16) & 1u);
  return (unsigned short)(u >> 16);
}

// ---------------- zero kernel ----------------
__global__ __launch_bounds__(256) void zero_kernel(float4* __restrict__ cov4,
                                                   float4* __restrict__ out4) {
  const int i = blockIdx.x * 256 + threadIdx.x;
  cov4[i] = make_float4(0.f, 0.f, 0.f, 0.f);
  if (i < 16) out4[i] = make_float4(0.f, 0.f, 0.f, 0.f);
}

// ---------------- prep kernels ----------------

__global__ __launch_bounds__(256) void mean_center_kernel(
    const float* __restrict__ sup, float* __restrict__ mean,
    unsigned short* __restrict__ Sb, int write_sb) {
  const int c = blockIdx.x;
  const int tid = threadIdx.x;
  float s = 0.f;
  for (int qd = tid; qd < 6400; qd += 256) {
    const int b = qd >> 8, s4 = (qd & 255) << 2;
    const float4 v = *(const float4*)(sup + ((size_t)b * CCH + c) * DSP + s4);
    s += v.x + v.y + v.z + v.w;
  }
  __shared__ float red[256];
  red[tid] = s;
  __syncthreads();
  for (int st = 128; st > 0; st >>= 1) {
    if (tid < st) red[tid] += red[tid + st];
    __syncthreads();
  }
  const float m = red[0] * (1.0f / 25600.0f);
  if (tid == 0) mean[c] = m;
  if (write_sb) {
    for (int qd = tid; qd < 6400; qd += 256) {
      const int b = qd >> 8, s4 = (qd & 255) << 2;
      const float4 v = *(const float4*)(sup + ((size_t)b * CCH + c) * DSP + s4);
      ushort4 o;
      o.x = f2bf(v.x - m); o.y = f2bf(v.y - m);
      o.z = f2bf(v.z - m); o.w = f2bf(v.w - m);
      *(ushort4*)(Sb + (size_t)c * NSUP + b * DSP + s4) = o;
    }
  }
}

__global__ __launch_bounds__(256) void qnorm_kernel(
    const float* __restrict__ q, float* __restrict__ qfac,
    unsigned short* __restrict__ Qb, int write_qb) {
  const int row = blockIdx.x * 4 + (threadIdx.x >> 6);
  const int l = threadIdx.x & 63;
  const float4* src = (const float4*)(q + (size_t)row * DSP);
  float4 v[4];
  float ss = 0.f;
#pragma unroll
  for (int i = 0; i < 4; ++i) {
    v[i] = src[l + 64 * i];
    ss += v[i].x * v[i].x + v[i].y * v[i].y + v[i].z * v[i].z + v[i].w * v[i].w;
  }
#pragma unroll
  for (int off = 32; off > 0; off >>= 1) ss += __shfl_xor(ss, off);
  const float f = 1.0f / (sqrtf(ss) + 1e-8f);
  if (l == 0) qfac[row] = f;
  if (write_qb) {
#pragma unroll
    for (int i = 0; i < 4; ++i) {
      ushort4 o;
      o.x = f2bf(v[i].x * f); o.y = f2bf(v[i].y * f);
      o.z = f2bf(v[i].z * f); o.w = f2bf(v[i].w * f);
      *(ushort4*)(Qb + (size_t)row * DSP + (size_t)(l + 64 * i) * 4) = o;
    }
  }
}

// ---------------- GEMM building blocks ----------------
// LDS layout: [128 rows][64 cols] bf16, XOR-swizzled: LDS[row][c ^ ((row&7)<<3)]
// holds logical (row, c). global_load_lds writes linearly, so the SOURCE column
// is pre-swizzled (rule #21: both-sides-or-neither).

// stage a 128x64 bf16 tile into swizzled LDS: exactly 4 global_load_lds per wave
__device__ inline void stage_glds(const unsigned short* __restrict__ src, int ld,
                                  int row0, int k0, unsigned short* lds) {
  const int tid = threadIdx.x;
  const int w = tid >> 6;
#pragma unroll
  for (int it = 0; it < 4; ++it) {
    const int ci = it * 256 + tid;          // chunk 0..1023 (16B each)
    const int r = ci >> 3;
    const int kc = ((ci & 7) ^ (r & 7)) << 3;   // pre-swizzled global col
    const unsigned short* g = src + (size_t)(row0 + r) * ld + k0 + kc;
    unsigned short* lb = lds + ((it * 256 + w * 64) << 3);  // wave-uniform
    __builtin_amdgcn_global_load_lds((const __attribute__((address_space(1))) void*)g,
                                     (__attribute__((address_space(3))) void*)lb,
                                     16, 0, 0);
  }
}

// compact-path staging: centered support from fp32 (swizzled ds_write)
__device__ inline void stage_sup_f32(const float* __restrict__ sup,
                                     const float* __restrict__ mean,
                                     int row0, int k0, unsigned short* lds) {
  const int tid = threadIdx.x;
#pragma unroll
  for (int it = 0; it < 4; ++it) {
    const int ci = it * 256 + tid;
    const int r = ci >> 3, kc = (ci & 7) << 3;
    const int c = row0 + r;
    const int k = k0 + kc;
    const int b = k >> 10, sp = k & 1023;
    const float4* g = (const float4*)(sup + ((size_t)b * CCH + c) * DSP + sp);
    const float4 v0 = g[0], v1 = g[1];
    const float m = mean[c];
    union { unsigned short h[8]; int4 q; } pk;
    pk.h[0] = f2bf(v0.x - m); pk.h[1] = f2bf(v0.y - m);
    pk.h[2] = f2bf(v0.z - m); pk.h[3] = f2bf(v0.w - m);
    pk.h[4] = f2bf(v1.x - m); pk.h[5] = f2bf(v1.y - m);
    pk.h[6] = f2bf(v1.z - m); pk.h[7] = f2bf(v1.w - m);
    *(int4*)(lds + (size_t)(r * 8 + ((ci & 7) ^ (r & 7))) * 8) = pk.q;
  }
}

// compact-path staging: normalized query from fp32 (swizzled ds_write)
__device__ inline void stage_q_f32(const float* __restrict__ qn,
                                   const float* __restrict__ qfacn,
                                   int row0, int k0, unsigned short* lds) {
  const int tid = threadIdx.x;
#pragma unroll
  for (int it = 0; it < 4; ++it) {
    const int ci = it * 256 + tid;
    const int r = ci >> 3, kc = (ci & 7) << 3;
    const int c = row0 + r;
    const float4* g = (const float4*)(qn + (size_t)c * DSP + k0 + kc);
    const float4 v0 = g[0], v1 = g[1];
    const float f = qfacn[c];
    union { unsigned short h[8]; int4 q; } pk;
    pk.h[0] = f2bf(v0.x * f); pk.h[1] = f2bf(v0.y * f);
    pk.h[2] = f2bf(v0.z * f); pk.h[3] = f2bf(v0.w * f);
    pk.h[4] = f2bf(v1.x * f); pk.h[5] = f2bf(v1.y * f);
    pk.h[6] = f2bf(v1.z * f); pk.h[7] = f2bf(v1.w * f);
    *(int4*)(lds + (size_t)(r * 8 + ((ci & 7) ^ (r & 7))) * 8) = pk.q;
  }
}

// one BK=64 compute step: 32 MFMAs per wave on 64x64 out sub-tile (swizzled read)
__device__ inline void compute_step(const unsigned short* lA, const unsigned short* lB,
                                    int wr, int wc, int lr, int kg, f32x4 acc[4][4]) {
  const int sc = (lr & 7) << 3;   // row&7 is lr&7 for every fragment row
  __builtin_amdgcn_s_setprio(1);
#pragma unroll
  for (int kk = 0; kk < 64; kk += 32) {
    const int col = (kk + kg) ^ sc;
    bf16x8 a[4], b[4];
#pragma unroll
    for (int i = 0; i < 4; ++i)
      a[i] = *(const bf16x8*)(const void*)(lA + (wr + i * 16 + lr) * 64 + col);
#pragma unroll
    for (int j = 0; j < 4; ++j)
      b[j] = *(const bf16x8*)(const void*)(lB + (wc + j * 16 + lr) * 64 + col);
#pragma unroll
    for (int i = 0; i < 4; ++i)
#pragma unroll
      for (int j = 0; j < 4; ++j)
        acc[i][j] = __builtin_amdgcn_mfma_f32_16x16x32_bf16(a[i], b[j], acc[i][j], 0, 0, 0);
  }
  __builtin_amdgcn_s_setprio(0);
}

// counted-vmcnt barrier pair (T4): tile-t loads drained, tile-(t+1) stay in flight
__device__ inline void pre_compute_sync_nondiag() {
  WAITVM(8);
  __builtin_amdgcn_s_barrier();
  __builtin_amdgcn_sched_barrier(0);
}
__device__ inline void pre_compute_sync_diag() {
  WAITVM(4);
  __builtin_amdgcn_s_barrier();
  __builtin_amdgcn_sched_barrier(0);
}
__device__ inline void pre_compute_sync_last() {
  WAITVM(0);
  __builtin_amdgcn_s_barrier();
  __builtin_amdgcn_sched_barrier(0);
}
__device__ inline void post_compute_sync() {
  WAITLGKM0();
  __builtin_amdgcn_s_barrier();
  __builtin_amdgcn_sched_barrier(0);
}

__device__ inline void decode_tile(int t, int& ti, int& tj) {
  int rem = t; ti = 0;
  while (rem >= 8 - ti) { rem -= 8 - ti; ++ti; }
  tj = ti + rem;
}

// ---------------- cov = centered @ centered^T / (N-1+eps), upper tiles only ----------------
// grid 1-D 288 = 36 pairs x 8 kslices; ks = wg&7 so each kslice's 36 blocks land
// on one XCD (its 6.5 MB Sb slice becomes L2-resident).
template <bool F32>
__global__ __launch_bounds__(256) void cov_kernel(
    const unsigned short* __restrict__ Sb, const float* __restrict__ sup,
    const float* __restrict__ mean, float* __restrict__ cov) {
  __shared__ unsigned short lA[2][128 * 64];
  __shared__ unsigned short lB[2][128 * 64];
  const int wg = blockIdx.x;
  const int ks = wg & 7;
  int ti, tj; decode_tile(wg >> 3, ti, tj);
  const bool diag = (ti == tj);
  const int tid = threadIdx.x, l = tid & 63, w = tid >> 6;
  const int wr = (w >> 1) * 64, wc = (w & 1) * 64, lr = l & 15, kg = (l >> 4) * 8;
  f32x4 acc[4][4];
#pragma unroll
  for (int i = 0; i < 4; ++i)
#pragma unroll
    for (int j = 0; j < 4; ++j) acc[i][j] = 0.f;

  const int kbase = ks * (NSUP / KSLICES);

  if (F32) {
    // fallback: reg-staged, classic 2-barrier loop
    stage_sup_f32(sup, mean, ti * 128, kbase, lA[0]);
    if (!diag) stage_sup_f32(sup, mean, tj * 128, kbase, lB[0]);
    __syncthreads();
    int cur = 0;
    for (int kt = 0; kt < NK_COV; ++kt) {
      if (kt + 1 < NK_COV) {
        const int k1 = kbase + (kt + 1) * 64;
        stage_sup_f32(sup, mean, ti * 128, k1, lA[cur ^ 1]);
        if (!diag) stage_sup_f32(sup, mean, tj * 128, k1, lB[cur ^ 1]);
      }
      compute_step(lA[cur], diag ? lA[cur] : lB[cur], wr, wc, lr, kg, acc);
      __syncthreads();
      cur ^= 1;
    }
  } else {
    // fat: global_load_lds + counted vmcnt (loads span 2 iterations)
    stage_glds(Sb, NSUP, ti * 128, kbase, lA[0]);
    if (!diag) stage_glds(Sb, NSUP, tj * 128, kbase, lB[0]);
    int cur = 0;
    for (int kt = 0; kt < NK_COV; ++kt) {
      if (kt + 1 < NK_COV) {
        const int k1 = kbase + (kt + 1) * 64;
        stage_glds(Sb, NSUP, ti * 128, k1, lA[cur ^ 1]);
        if (!diag) {
          stage_glds(Sb, NSUP, tj * 128, k1, lB[cur ^ 1]);
          pre_compute_sync_nondiag();
        } else {
          pre_compute_sync_diag();
        }
      } else {
        pre_compute_sync_last();
      }
      compute_step(lA[cur], diag ? lA[cur] : lB[cur], wr, wc, lr, kg, acc);
      post_compute_sync();
      cur ^= 1;
    }
  }

  const float scale = 1.0f / (25599.0f + 1e-8f);
  const int rbase = ti * 128 + wr + (l >> 4) * 4;
  const int cbase = tj * 128 + wc + (l & 15);
#pragma unroll
  for (int i = 0; i < 4; ++i)
#pragma unroll
    for (int j = 0; j < 4; ++j)
#pragma unroll
      for (int r = 0; r < 4; ++r)
        atomicAdd(&cov[(size_t)(rbase + i * 16 + r) * CCH + cbase + j * 16],
                  acc[i][j][r] * scale);
}

// ---------------- per-query Gram GEMM fused with cov Frobenius product ----------------
// 1-D grid 2304 = 8 xcd * 8 n-per-xcd * 36 tile-pairs: same-n blocks share an XCD's L2.
template <bool F32>
__global__ __launch_bounds__(256) void gram_kernel(
    const unsigned short* __restrict__ Qb, const float* __restrict__ q,
    const float* __restrict__ qfac, const float* __restrict__ cov,
    float* __restrict__ out) {
  __shared__ unsigned short lA[2][128 * 64];
  __shared__ unsigned short lB[2][128 * 64];
  const int wg = blockIdx.x;
  const int xcd = wg & 7, slot = wg >> 3;       // slot 0..287
  const int n = xcd * 8 + slot / 36;
  int ti, tj; decode_tile(slot % 36, ti, tj);
  const bool diag = (ti == tj);
  const int tid = threadIdx.x, l = tid & 63, w = tid >> 6;
  const int wr = (w >> 1) * 64, wc = (w & 1) * 64, lr = l & 15, kg = (l >> 4) * 8;
  f32x4 acc[4][4];
#pragma unroll
  for (int i = 0; i < 4; ++i)
#pragma unroll
    for (int j = 0; j < 4; ++j) acc[i][j] = 0.f;

  const unsigned short* Qn = Qb + (size_t)n * CCH * DSP;
  const float* qn = q + (size_t)n * CCH * DSP;
  const float* qfacn = qfac + (size_t)n * CCH;

  if (F32) {
    stage_q_f32(qn, qfacn, ti * 128, 0, lA[0]);
    if (!diag) stage_q_f32(qn, qfacn, tj * 128, 0, lB[0]);
    __syncthreads();
    int cur = 0;
    for (int kt = 0; kt < 16; ++kt) {
      if (kt + 1 < 16) {
        const int k1 = (kt + 1) * 64;
        stage_q_f32(qn, qfacn, ti * 128, k1, lA[cur ^ 1]);
        if (!diag) stage_q_f32(qn, qfacn, tj * 128, k1, lB[cur ^ 1]);
      }
      compute_step(lA[cur], diag ? lA[cur] : lB[cur], wr, wc, lr, kg, acc);
      __syncthreads();
      cur ^= 1;
    }
  } else {
    stage_glds(Qn, DSP, ti * 128, 0, lA[0]);
    if (!diag) stage_glds(Qn, DSP, tj * 128, 0, lB[0]);
    int cur = 0;
    for (int kt = 0; kt < 16; ++kt) {
      if (kt + 1 < 16) {
        const int k1 = (kt + 1) * 64;
        stage_glds(Qn, DSP, ti * 128, k1, lA[cur ^ 1]);
        if (!diag) {
          stage_glds(Qn, DSP, tj * 128, k1, lB[cur ^ 1]);
          pre_compute_sync_nondiag();
        } else {
          pre_compute_sync_diag();
        }
      } else {
        pre_compute_sync_last();
      }
      compute_step(lA[cur], diag ? lA[cur] : lB[cur], wr, wc, lr, kg, acc);
      post_compute_sync();
      cur ^= 1;
    }
  }

  float s = 0.f;
  const int rbase = ti * 128 + wr + (l >> 4) * 4;
  const int cbase = tj * 128 + wc + (l & 15);
#pragma unroll
  for (int i = 0; i < 4; ++i)
#pragma unroll
    for (int j = 0; j < 4; ++j)
#pragma unroll
      for (int r = 0; r < 4; ++r)
        s += acc[i][j][r] * cov[(size_t)(rbase + i * 16 + r) * CCH + cbase + j * 16];
  if (!diag) s *= 2.0f;
  s *= (1.0f / 1024.0f);
#pragma unroll
  for (int off = 32; off > 0; off >>= 1) s += __shfl_xor(s, off);
  if (l == 0) atomicAdd(&out[n], s);
}

// ---------------- launch ----------------
extern "C" void kernel_launch(void* const* d_in, const int* in_sizes, int n_in,
                              void* d_out, int out_size, void* d_ws, size_t ws_size,
                              hipStream_t stream) {
  const float* q = (const float*)d_in[0];
  const float* sup = (const float*)d_in[1];
  float* out = (float*)d_out;

  char* ws = (char*)d_ws;
  float* mean = (float*)ws;                                  // 4 KB
  float* qfac = (float*)(ws + (4 << 10));                    // 256 KB
  float* cov  = (float*)(ws + (4 << 10) + (256 << 10));      // 4 MB
  unsigned short* Sb = (unsigned short*)(ws + (4 << 10) + (256 << 10) + (4 << 20));
  unsigned short* Qb = Sb + (size_t)CCH * NSUP;
  const size_t need_fat = (size_t)(4 << 10) + (256 << 10) + (4 << 20) +
                          (size_t)CCH * NSUP * 2 + (size_t)NQ * CCH * DSP * 2;
  const bool fat = ws_size >= need_fat;

  zero_kernel<<<1024, 256, 0, stream>>>((float4*)cov, (float4*)out);

  mean_center_kernel<<<CCH, 256, 0, stream>>>(sup, mean, Sb, fat ? 1 : 0);
  qnorm_kernel<<<NQ * CCH / 4, 256, 0, stream>>>(q, qfac, Qb, fat ? 1 : 0);

  if (fat) {
    cov_kernel<false><<<dim3(288), 256, 0, stream>>>(Sb, sup, mean, cov);
    gram_kernel<false><<<dim3(8 * 8 * 36), 256, 0, stream>>>(Qb, q, qfac, cov, out);
  } else {
    cov_kernel<true><<<dim3(288), 256, 0, stream>>>(Sb, sup, mean, cov);
    gram_kernel<true><<<dim3(8 * 8 * 36), 256, 0, stream>>>(Qb, q, qfac, cov, out);
  }
}

// Round 6
// 301.884 us; speedup vs baseline: 1.3171x; 1.0058x over previous
//
#include <hip/hip_runtime.h>

#define NQ   64
#define CCH  1024
#define DSP  1024      // 32*32 spatial
#define NSUP 25600     // 25*32*32
#define KSLICES 8
#define NK_COV 50      // 25600/8/64

typedef __attribute__((ext_vector_type(4))) float f32x4;
typedef __attribute__((ext_vector_type(8))) __bf16 bf16x8;

#define WAITVM(N) asm volatile("s_waitcnt vmcnt(" #N ")" ::: "memory")
#define WAITLGKM0() asm volatile("s_waitcnt lgkmcnt(0)" ::: "memory")
#define BAR() __builtin_amdgcn_s_barrier()

__device__ inline unsigned short f2bf(float x) {
  unsigned u = __builtin_bit_cast(unsigned, x);
  u += 0x7fffu + ((u >> 16) & 1u);
  return (unsigned short)(u >> 16);
}

// ---------------- zero kernel ----------------
__global__ __launch_bounds__(256) void zero_kernel(float4* __restrict__ cov4,
                                                   float4* __restrict__ out4) {
  const int i = blockIdx.x * 256 + threadIdx.x;
  cov4[i] = make_float4(0.f, 0.f, 0.f, 0.f);
  if (i < 16) out4[i] = make_float4(0.f, 0.f, 0.f, 0.f);
}

// ---------------- prep kernels ----------------

__global__ __launch_bounds__(256) void mean_center_kernel(
    const float* __restrict__ sup, float* __restrict__ mean,
    unsigned short* __restrict__ Sb, int write_sb) {
  const int c = blockIdx.x;
  const int tid = threadIdx.x;
  float s = 0.f;
  for (int qd = tid; qd < 6400; qd += 256) {
    const int b = qd >> 8, s4 = (qd & 255) << 2;
    const float4 v = *(const float4*)(sup + ((size_t)b * CCH + c) * DSP + s4);
    s += v.x + v.y + v.z + v.w;
  }
  __shared__ float red[256];
  red[tid] = s;
  __syncthreads();
  for (int st = 128; st > 0; st >>= 1) {
    if (tid < st) red[tid] += red[tid + st];
    __syncthreads();
  }
  const float m = red[0] * (1.0f / 25600.0f);
  if (tid == 0) mean[c] = m;
  if (write_sb) {
    for (int qd = tid; qd < 6400; qd += 256) {
      const int b = qd >> 8, s4 = (qd & 255) << 2;
      const float4 v = *(const float4*)(sup + ((size_t)b * CCH + c) * DSP + s4);
      ushort4 o;
      o.x = f2bf(v.x - m); o.y = f2bf(v.y - m);
      o.z = f2bf(v.z - m); o.w = f2bf(v.w - m);
      *(ushort4*)(Sb + (size_t)c * NSUP + b * DSP + s4) = o;
    }
  }
}

__global__ __launch_bounds__(256) void qnorm_kernel(
    const float* __restrict__ q, float* __restrict__ qfac,
    unsigned short* __restrict__ Qb, int write_qb) {
  const int row = blockIdx.x * 4 + (threadIdx.x >> 6);
  const int l = threadIdx.x & 63;
  const float4* src = (const float4*)(q + (size_t)row * DSP);
  float4 v[4];
  float ss = 0.f;
#pragma unroll
  for (int i = 0; i < 4; ++i) {
    v[i] = src[l + 64 * i];
    ss += v[i].x * v[i].x + v[i].y * v[i].y + v[i].z * v[i].z + v[i].w * v[i].w;
  }
#pragma unroll
  for (int off = 32; off > 0; off >>= 1) ss += __shfl_xor(ss, off);
  const float f = 1.0f / (sqrtf(ss) + 1e-8f);
  if (l == 0) qfac[row] = f;
  if (write_qb) {
#pragma unroll
    for (int i = 0; i < 4; ++i) {
      ushort4 o;
      o.x = f2bf(v[i].x * f); o.y = f2bf(v[i].y * f);
      o.z = f2bf(v[i].z * f); o.w = f2bf(v[i].w * f);
      *(ushort4*)(Qb + (size_t)row * DSP + (size_t)(l + 64 * i) * 4) = o;
    }
  }
}

// ---------------- 128-tile GEMM building blocks (cov + fallback) ----------------
// LDS layout: [128 rows][64 cols] bf16, XOR-swizzled: LDS[row][c ^ ((row&7)<<3)].

__device__ inline void stage_glds(const unsigned short* __restrict__ src, int ld,
                                  int row0, int k0, unsigned short* lds) {
  const int tid = threadIdx.x;
  const int w = tid >> 6;
#pragma unroll
  for (int it = 0; it < 4; ++it) {
    const int ci = it * 256 + tid;          // chunk 0..1023 (16B each)
    const int r = ci >> 3;
    const int kc = ((ci & 7) ^ (r & 7)) << 3;   // pre-swizzled global col
    const unsigned short* g = src + (size_t)(row0 + r) * ld + k0 + kc;
    unsigned short* lb = lds + ((it * 256 + w * 64) << 3);  // wave-uniform
    __builtin_amdgcn_global_load_lds((const __attribute__((address_space(1))) void*)g,
                                     (__attribute__((address_space(3))) void*)lb,
                                     16, 0, 0);
  }
}

__device__ inline void stage_sup_f32(const float* __restrict__ sup,
                                     const float* __restrict__ mean,
                                     int row0, int k0, unsigned short* lds) {
  const int tid = threadIdx.x;
#pragma unroll
  for (int it = 0; it < 4; ++it) {
    const int ci = it * 256 + tid;
    const int r = ci >> 3, kc = (ci & 7) << 3;
    const int c = row0 + r;
    const int k = k0 + kc;
    const int b = k >> 10, sp = k & 1023;
    const float4* g = (const float4*)(sup + ((size_t)b * CCH + c) * DSP + sp);
    const float4 v0 = g[0], v1 = g[1];
    const float m = mean[c];
    union { unsigned short h[8]; int4 q; } pk;
    pk.h[0] = f2bf(v0.x - m); pk.h[1] = f2bf(v0.y - m);
    pk.h[2] = f2bf(v0.z - m); pk.h[3] = f2bf(v0.w - m);
    pk.h[4] = f2bf(v1.x - m); pk.h[5] = f2bf(v1.y - m);
    pk.h[6] = f2bf(v1.z - m); pk.h[7] = f2bf(v1.w - m);
    *(int4*)(lds + (size_t)(r * 8 + ((ci & 7) ^ (r & 7))) * 8) = pk.q;
  }
}

__device__ inline void stage_q_f32(const float* __restrict__ qn,
                                   const float* __restrict__ qfacn,
                                   int row0, int k0, unsigned short* lds) {
  const int tid = threadIdx.x;
#pragma unroll
  for (int it = 0; it < 4; ++it) {
    const int ci = it * 256 + tid;
    const int r = ci >> 3, kc = (ci & 7) << 3;
    const int c = row0 + r;
    const float4* g = (const float4*)(qn + (size_t)c * DSP + k0 + kc);
    const float4 v0 = g[0], v1 = g[1];
    const float f = qfacn[c];
    union { unsigned short h[8]; int4 q; } pk;
    pk.h[0] = f2bf(v0.x * f); pk.h[1] = f2bf(v0.y * f);
    pk.h[2] = f2bf(v0.z * f); pk.h[3] = f2bf(v0.w * f);
    pk.h[4] = f2bf(v1.x * f); pk.h[5] = f2bf(v1.y * f);
    pk.h[6] = f2bf(v1.z * f); pk.h[7] = f2bf(v1.w * f);
    *(int4*)(lds + (size_t)(r * 8 + ((ci & 7) ^ (r & 7))) * 8) = pk.q;
  }
}

__device__ inline void compute_step(const unsigned short* lA, const unsigned short* lB,
                                    int wr, int wc, int lr, int kg, f32x4 acc[4][4]) {
  const int sc = (lr & 7) << 3;
  __builtin_amdgcn_s_setprio(1);
#pragma unroll
  for (int kk = 0; kk < 64; kk += 32) {
    const int col = (kk + kg) ^ sc;
    bf16x8 a[4], b[4];
#pragma unroll
    for (int i = 0; i < 4; ++i)
      a[i] = *(const bf16x8*)(const void*)(lA + (wr + i * 16 + lr) * 64 + col);
#pragma unroll
    for (int j = 0; j < 4; ++j)
      b[j] = *(const bf16x8*)(const void*)(lB + (wc + j * 16 + lr) * 64 + col);
#pragma unroll
    for (int i = 0; i < 4; ++i)
#pragma unroll
      for (int j = 0; j < 4; ++j)
        acc[i][j] = __builtin_amdgcn_mfma_f32_16x16x32_bf16(a[i], b[j], acc[i][j], 0, 0, 0);
  }
  __builtin_amdgcn_s_setprio(0);
}

__device__ inline void pre_compute_sync_nondiag() {
  WAITVM(8); BAR(); __builtin_amdgcn_sched_barrier(0);
}
__device__ inline void pre_compute_sync_diag() {
  WAITVM(4); BAR(); __builtin_amdgcn_sched_barrier(0);
}
__device__ inline void pre_compute_sync_last() {
  WAITVM(0); BAR(); __builtin_amdgcn_sched_barrier(0);
}
__device__ inline void post_compute_sync() {
  WAITLGKM0(); BAR(); __builtin_amdgcn_sched_barrier(0);
}

__device__ inline void decode_tile(int t, int& ti, int& tj) {
  int rem = t; ti = 0;
  while (rem >= 8 - ti) { rem -= 8 - ti; ++ti; }
  tj = ti + rem;
}

// ---------------- cov = centered @ centered^T / (N-1+eps), upper tiles only ----------------
template <bool F32>
__global__ __launch_bounds__(256) void cov_kernel(
    const unsigned short* __restrict__ Sb, const float* __restrict__ sup,
    const float* __restrict__ mean, float* __restrict__ cov) {
  __shared__ unsigned short lA[2][128 * 64];
  __shared__ unsigned short lB[2][128 * 64];
  const int wg = blockIdx.x;
  const int ks = wg & 7;
  int ti, tj; decode_tile(wg >> 3, ti, tj);
  const bool diag = (ti == tj);
  const int tid = threadIdx.x, l = tid & 63, w = tid >> 6;
  const int wr = (w >> 1) * 64, wc = (w & 1) * 64, lr = l & 15, kg = (l >> 4) * 8;
  f32x4 acc[4][4];
#pragma unroll
  for (int i = 0; i < 4; ++i)
#pragma unroll
    for (int j = 0; j < 4; ++j) acc[i][j] = 0.f;

  const int kbase = ks * (NSUP / KSLICES);

  if (F32) {
    stage_sup_f32(sup, mean, ti * 128, kbase, lA[0]);
    if (!diag) stage_sup_f32(sup, mean, tj * 128, kbase, lB[0]);
    __syncthreads();
    int cur = 0;
    for (int kt = 0; kt < NK_COV; ++kt) {
      if (kt + 1 < NK_COV) {
        const int k1 = kbase + (kt + 1) * 64;
        stage_sup_f32(sup, mean, ti * 128, k1, lA[cur ^ 1]);
        if (!diag) stage_sup_f32(sup, mean, tj * 128, k1, lB[cur ^ 1]);
      }
      compute_step(lA[cur], diag ? lA[cur] : lB[cur], wr, wc, lr, kg, acc);
      __syncthreads();
      cur ^= 1;
    }
  } else {
    stage_glds(Sb, NSUP, ti * 128, kbase, lA[0]);
    if (!diag) stage_glds(Sb, NSUP, tj * 128, kbase, lB[0]);
    int cur = 0;
    for (int kt = 0; kt < NK_COV; ++kt) {
      if (kt + 1 < NK_COV) {
        const int k1 = kbase + (kt + 1) * 64;
        stage_glds(Sb, NSUP, ti * 128, k1, lA[cur ^ 1]);
        if (!diag) {
          stage_glds(Sb, NSUP, tj * 128, k1, lB[cur ^ 1]);
          pre_compute_sync_nondiag();
        } else {
          pre_compute_sync_diag();
        }
      } else {
        pre_compute_sync_last();
      }
      compute_step(lA[cur], diag ? lA[cur] : lB[cur], wr, wc, lr, kg, acc);
      post_compute_sync();
      cur ^= 1;
    }
  }

  const float scale = 1.0f / (25599.0f + 1e-8f);
  const int rbase = ti * 128 + wr + (l >> 4) * 4;
  const int cbase = tj * 128 + wc + (l & 15);
#pragma unroll
  for (int i = 0; i < 4; ++i)
#pragma unroll
    for (int j = 0; j < 4; ++j)
#pragma unroll
      for (int r = 0; r < 4; ++r)
        atomicAdd(&cov[(size_t)(rbase + i * 16 + r) * CCH + cbase + j * 16],
                  acc[i][j][r] * scale);
}

// ---------------- fallback (thin ws) 128-tile gram ----------------
template <bool F32>
__global__ __launch_bounds__(256) void gram_kernel(
    const unsigned short* __restrict__ Qb, const float* __restrict__ q,
    const float* __restrict__ qfac, const float* __restrict__ cov,
    float* __restrict__ out) {
  __shared__ unsigned short lA[2][128 * 64];
  __shared__ unsigned short lB[2][128 * 64];
  const int wg = blockIdx.x;
  const int xcd = wg & 7, slot = wg >> 3;
  const int n = xcd * 8 + slot / 36;
  int ti, tj; decode_tile(slot % 36, ti, tj);
  const bool diag = (ti == tj);
  const int tid = threadIdx.x, l = tid & 63, w = tid >> 6;
  const int wr = (w >> 1) * 64, wc = (w & 1) * 64, lr = l & 15, kg = (l >> 4) * 8;
  f32x4 acc[4][4];
#pragma unroll
  for (int i = 0; i < 4; ++i)
#pragma unroll
    for (int j = 0; j < 4; ++j) acc[i][j] = 0.f;

  const float* qn = q + (size_t)n * CCH * DSP;
  const float* qfacn = qfac + (size_t)n * CCH;

  stage_q_f32(qn, qfacn, ti * 128, 0, lA[0]);
  if (!diag) stage_q_f32(qn, qfacn, tj * 128, 0, lB[0]);
  __syncthreads();
  int cur = 0;
  for (int kt = 0; kt < 16; ++kt) {
    if (kt + 1 < 16) {
      const int k1 = (kt + 1) * 64;
      stage_q_f32(qn, qfacn, ti * 128, k1, lA[cur ^ 1]);
      if (!diag) stage_q_f32(qn, qfacn, tj * 128, k1, lB[cur ^ 1]);
    }
    compute_step(lA[cur], diag ? lA[cur] : lB[cur], wr, wc, lr, kg, acc);
    __syncthreads();
    cur ^= 1;
  }

  float s = 0.f;
  const int rbase = ti * 128 + wr + (l >> 4) * 4;
  const int cbase = tj * 128 + wc + (l & 15);
#pragma unroll
  for (int i = 0; i < 4; ++i)
#pragma unroll
    for (int j = 0; j < 4; ++j)
#pragma unroll
      for (int r = 0; r < 4; ++r)
        s += acc[i][j][r] * cov[(size_t)(rbase + i * 16 + r) * CCH + cbase + j * 16];
  if (!diag) s *= 2.0f;
  s *= (1.0f / 1024.0f);
#pragma unroll
  for (int off = 32; off > 0; off >>= 1) s += __shfl_xor(s, off);
  if (l == 0) atomicAdd(&out[n], s);
}

// ---------------- 256x256 8-wave phase-split gram ----------------
// BM=BN=256, BK=64, 512 thr (8 waves: 2M x 4N), per-wave 128x64, acc[8][4].
// LDS 128 KB: buf b at b*32768 elems: A [0,16384), B [16384,32768).
// A/B tile layout: (r>>7)*8192 + (r&127)*64 + (c ^ ((r&7)<<3))  (elems).

__device__ inline void stage256(const unsigned short* __restrict__ src,
                                int row0, int k0, unsigned short* lds_base) {
  const int tid = threadIdx.x;
  const int wid = tid >> 6;
#pragma unroll
  for (int it = 0; it < 4; ++it) {
    const int ci = it * 512 + tid;          // chunk 0..2047 (16B each)
    const int r = ci >> 3;
    const int kc = ((ci & 7) ^ (r & 7)) << 3;   // pre-swizzled global col
    const unsigned short* g = src + (size_t)(row0 + r) * DSP + k0 + kc;
    unsigned short* lb = lds_base + ((it * 512 + (wid << 6)) << 3);  // wave-uniform
    __builtin_amdgcn_global_load_lds((const __attribute__((address_space(1))) void*)g,
                                     (__attribute__((address_space(3))) void*)lb,
                                     16, 0, 0);
  }
}

__device__ inline void rd_a4(const unsigned short* A, int q, int col, int lr, bf16x8 a[4]) {
#pragma unroll
  for (int i = 0; i < 4; ++i)
    a[i] = *(const bf16x8*)(const void*)(A + (q * 64 + i * 16 + lr) * 64 + col);
}
__device__ inline void rd_b4(const unsigned short* B, int brow, int col, int lr, bf16x8 b[4]) {
#pragma unroll
  for (int j = 0; j < 4; ++j)
    b[j] = *(const bf16x8*)(const void*)(B + (brow + j * 16 + lr) * 64 + col);
}
__device__ inline void mfma16(const bf16x8 a[4], const bf16x8 b[4], f32x4 (*acc)[4]) {
  __builtin_amdgcn_s_setprio(1);
#pragma unroll
  for (int i = 0; i < 4; ++i)
#pragma unroll
    for (int j = 0; j < 4; ++j)
      acc[i][j] = __builtin_amdgcn_mfma_f32_16x16x32_bf16(a[i], b[j], acc[i][j], 0, 0, 0);
  __builtin_amdgcn_s_setprio(0);
}

__global__ __launch_bounds__(512, 2) void gram256_kernel(
    const unsigned short* __restrict__ Qb, const float* __restrict__ cov,
    float* __restrict__ out) {
  __shared__ unsigned short lds[65536];   // 128 KB
  const int wg = blockIdx.x;
  const int xcd = wg & 7, slot = wg >> 3;        // slot 0..79
  const int n = xcd * 8 + slot / 10;
  int rem = slot % 10, ti = 0;
  while (rem >= 4 - ti) { rem -= 4 - ti; ++ti; }
  const int tj = ti + rem;
  const int tid = threadIdx.x, l = tid & 63, wid = tid >> 6;
  const int wm = wid >> 2, wn = wid & 3;
  const int lr = l & 15, kg = (l >> 4) * 8;
  const int sw = (lr & 7) << 3;
  const unsigned short* Qn = Qb + (size_t)n * CCH * DSP;

  f32x4 acc[8][4];
#pragma unroll
  for (int i = 0; i < 8; ++i)
#pragma unroll
    for (int j = 0; j < 4; ++j) acc[i][j] = 0.f;

  // prologue: tile 0 -> buf 0
  stage256(Qn, ti * 256, 0, lds);
  stage256(Qn, tj * 256, 0, lds + 16384);
  WAITVM(0);
  BAR();

  for (int t = 0; t < 16; ++t) {
    const int cb = (t & 1) << 15;          // current buf base (elems)
    if (t < 15) {
      const int nb = cb ^ 32768;
      stage256(Qn, ti * 256, (t + 1) * 64, lds + nb);
      stage256(Qn, tj * 256, (t + 1) * 64, lds + nb + 16384);
    }
    const unsigned short* A = lds + cb + wm * 8192;
    const unsigned short* B = lds + cb + 16384 + (wn >> 1) * 8192;
    const int brow = (wn & 1) * 64;
    bf16x8 a[4], b[4];
#pragma unroll
    for (int kk = 0; kk < 64; kk += 32) {
      const int col = (kk + kg) ^ sw;
      // phase A: M-half 0
      rd_b4(B, brow, col, lr, b);
      rd_a4(A, 0, col, lr, a);
      BAR();
      mfma16(a, b, &acc[0]);
      BAR();
      // phase B: M-half 1 (reuse b)
      rd_a4(A, 1, col, lr, a);
      BAR();
      mfma16(a, b, &acc[4]);
      if (kk == 32 && t < 15) WAITVM(0);
      BAR();
    }
  }

  float s = 0.f;
  const int rbase = ti * 256 + wm * 128 + (l >> 4) * 4;
  const int cbase = tj * 256 + wn * 64 + (l & 15);
#pragma unroll
  for (int i = 0; i < 8; ++i)
#pragma unroll
    for (int j = 0; j < 4; ++j)
#pragma unroll
      for (int r = 0; r < 4; ++r)
        s += acc[i][j][r] * cov[(size_t)(rbase + i * 16 + r) * CCH + cbase + j * 16];
  if (ti != tj) s *= 2.0f;
  s *= (1.0f / 1024.0f);
#pragma unroll
  for (int off = 32; off > 0; off >>= 1) s += __shfl_xor(s, off);
  if (l == 0) atomicAdd(&out[n], s);
}

// ---------------- launch ----------------
extern "C" void kernel_launch(void* const* d_in, const int* in_sizes, int n_in,
                              void* d_out, int out_size, void* d_ws, size_t ws_size,
                              hipStream_t stream) {
  const float* q = (const float*)d_in[0];
  const float* sup = (const float*)d_in[1];
  float* out = (float*)d_out;

  char* ws = (char*)d_ws;
  float* mean = (float*)ws;                                  // 4 KB
  float* qfac = (float*)(ws + (4 << 10));                    // 256 KB
  float* cov  = (float*)(ws + (4 << 10) + (256 << 10));      // 4 MB
  unsigned short* Sb = (unsigned short*)(ws + (4 << 10) + (256 << 10) + (4 << 20));
  unsigned short* Qb = Sb + (size_t)CCH * NSUP;
  const size_t need_fat = (size_t)(4 << 10) + (256 << 10) + (4 << 20) +
                          (size_t)CCH * NSUP * 2 + (size_t)NQ * CCH * DSP * 2;
  const bool fat = ws_size >= need_fat;

  zero_kernel<<<1024, 256, 0, stream>>>((float4*)cov, (float4*)out);

  mean_center_kernel<<<CCH, 256, 0, stream>>>(sup, mean, Sb, fat ? 1 : 0);
  qnorm_kernel<<<NQ * CCH / 4, 256, 0, stream>>>(q, qfac, Qb, fat ? 1 : 0);

  if (fat) {
    cov_kernel<false><<<dim3(288), 256, 0, stream>>>(Sb, sup, mean, cov);
    gram256_kernel<<<dim3(640), 512, 0, stream>>>(Qb, cov, out);
  } else {
    cov_kernel<true><<<dim3(288), 256, 0, stream>>>(Sb, sup, mean, cov);
    gram_kernel<true><<<dim3(8 * 8 * 36), 256, 0, stream>>>(Qb, q, qfac, cov, out);
  }
}

// Round 7
// 270.399 us; speedup vs baseline: 1.4704x; 1.1164x over previous
//
#include <hip/hip_runtime.h>

#define NQ   64
#define CCH  1024
#define DSP  1024      // 32*32 spatial
#define NSUP 25600     // 25*32*32
#define KSLICES 8
#define NK_COV 50      // 25600/8/64

typedef __attribute__((ext_vector_type(4))) float f32x4;
typedef __attribute__((ext_vector_type(8))) __bf16 bf16x8;

#define WAITVM(N) asm volatile("s_waitcnt vmcnt(" #N ")" ::: "memory")
#define WAITLGKM0() asm volatile("s_waitcnt lgkmcnt(0)" ::: "memory")
#define BAR() __builtin_amdgcn_s_barrier()
#define SCHED0() __builtin_amdgcn_sched_barrier(0)

__device__ inline unsigned short f2bf(float x) {
  unsigned u = __builtin_bit_cast(unsigned, x);
  u += 0x7fffu + ((u >> 16) & 1u);
  return (unsigned short)(u >> 16);
}

// ---------------- zero kernel ----------------
__global__ __launch_bounds__(256) void zero_kernel(float4* __restrict__ cov4,
                                                   float4* __restrict__ out4) {
  const int i = blockIdx.x * 256 + threadIdx.x;
  cov4[i] = make_float4(0.f, 0.f, 0.f, 0.f);
  if (i < 16) out4[i] = make_float4(0.f, 0.f, 0.f, 0.f);
}

// ---------------- prep kernels ----------------

// one block per channel c: single HBM pass — row cached in LDS (100 KB),
// mean reduce, then center+cast from LDS.
__global__ __launch_bounds__(512) void mean_center_kernel(
    const float* __restrict__ sup, float* __restrict__ mean,
    unsigned short* __restrict__ Sb, int write_sb) {
  __shared__ float4 row[6400];     // 100 KB
  __shared__ float red[512];
  const int c = blockIdx.x;
  const int tid = threadIdx.x;
  float s = 0.f;
  for (int qd = tid; qd < 6400; qd += 512) {
    const int b = qd >> 8, s4 = (qd & 255) << 2;
    const float4 v = *(const float4*)(sup + ((size_t)b * CCH + c) * DSP + s4);
    row[qd] = v;
    s += v.x + v.y + v.z + v.w;
  }
  red[tid] = s;
  __syncthreads();
  for (int st = 256; st > 0; st >>= 1) {
    if (tid < st) red[tid] += red[tid + st];
    __syncthreads();
  }
  const float m = red[0] * (1.0f / 25600.0f);
  if (tid == 0) mean[c] = m;
  if (write_sb) {
    for (int qd = tid; qd < 6400; qd += 512) {
      const float4 v = row[qd];
      const int b = qd >> 8, s4 = (qd & 255) << 2;
      ushort4 o;
      o.x = f2bf(v.x - m); o.y = f2bf(v.y - m);
      o.z = f2bf(v.z - m); o.w = f2bf(v.w - m);
      *(ushort4*)(Sb + (size_t)c * NSUP + b * DSP + s4) = o;
    }
  }
}

// one wave per (n,c) row of 1024: L2 norm factor, optionally write bf16 Qb
__global__ __launch_bounds__(256) void qnorm_kernel(
    const float* __restrict__ q, float* __restrict__ qfac,
    unsigned short* __restrict__ Qb, int write_qb) {
  const int row = blockIdx.x * 4 + (threadIdx.x >> 6);
  const int l = threadIdx.x & 63;
  const float4* src = (const float4*)(q + (size_t)row * DSP);
  float4 v[4];
  float ss = 0.f;
#pragma unroll
  for (int i = 0; i < 4; ++i) {
    v[i] = src[l + 64 * i];
    ss += v[i].x * v[i].x + v[i].y * v[i].y + v[i].z * v[i].z + v[i].w * v[i].w;
  }
#pragma unroll
  for (int off = 32; off > 0; off >>= 1) ss += __shfl_xor(ss, off);
  const float f = 1.0f / (sqrtf(ss) + 1e-8f);
  if (l == 0) qfac[row] = f;
  if (write_qb) {
#pragma unroll
    for (int i = 0; i < 4; ++i) {
      ushort4 o;
      o.x = f2bf(v[i].x * f); o.y = f2bf(v[i].y * f);
      o.z = f2bf(v[i].z * f); o.w = f2bf(v[i].w * f);
      *(ushort4*)(Qb + (size_t)row * DSP + (size_t)(l + 64 * i) * 4) = o;
    }
  }
}

// ---------------- shared GEMM helpers ----------------
// LDS tiles XOR-swizzled: logical (r,c) at r*64 + (c ^ ((r&7)<<3)).
// global_load_lds writes linearly -> SOURCE column pre-swizzled (rule #21).

// stage a 128x64 bf16 tile (256-thread blocks): 4 loads per thread
__device__ inline void stage_glds(const unsigned short* __restrict__ src, int ld,
                                  int row0, int k0, unsigned short* lds) {
  const int tid = threadIdx.x;
  const int w = tid >> 6;
#pragma unroll
  for (int it = 0; it < 4; ++it) {
    const int ci = it * 256 + tid;
    const int r = ci >> 3;
    const int kc = ((ci & 7) ^ (r & 7)) << 3;
    const unsigned short* g = src + (size_t)(row0 + r) * ld + k0 + kc;
    unsigned short* lb = lds + ((it * 256 + w * 64) << 3);
    __builtin_amdgcn_global_load_lds((const __attribute__((address_space(1))) void*)g,
                                     (__attribute__((address_space(3))) void*)lb,
                                     16, 0, 0);
  }
}

// stage a 256x64 bf16 tile (512-thread blocks): 4 loads per thread
// layout: (r>>7)*8192 + (r&127)*64 + swizzled col
__device__ inline void stage256(const unsigned short* __restrict__ src,
                                int row0, int k0, unsigned short* lds_base) {
  const int tid = threadIdx.x;
  const int wid = tid >> 6;
#pragma unroll
  for (int it = 0; it < 4; ++it) {
    const int ci = it * 512 + tid;          // chunk 0..2047 (16B each)
    const int r = ci >> 3;
    const int kc = ((ci & 7) ^ (r & 7)) << 3;
    const unsigned short* g = src + (size_t)(row0 + r) * DSP + k0 + kc;
    unsigned short* lb = lds_base + ((it * 512 + (wid << 6)) << 3);
    __builtin_amdgcn_global_load_lds((const __attribute__((address_space(1))) void*)g,
                                     (__attribute__((address_space(3))) void*)lb,
                                     16, 0, 0);
  }
}

__device__ inline void rd4(const unsigned short* base, int r0, int col, int lr, bf16x8 f[4]) {
#pragma unroll
  for (int i = 0; i < 4; ++i)
    f[i] = *(const bf16x8*)(const void*)(base + (r0 + i * 16 + lr) * 64 + col);
}
__device__ inline void mfma16(const bf16x8 a[4], const bf16x8 b[4], f32x4 (*acc)[4]) {
  __builtin_amdgcn_s_setprio(1);
#pragma unroll
  for (int i = 0; i < 4; ++i)
#pragma unroll
    for (int j = 0; j < 4; ++j)
      acc[i][j] = __builtin_amdgcn_mfma_f32_16x16x32_bf16(a[i], b[j], acc[i][j], 0, 0, 0);
  __builtin_amdgcn_s_setprio(0);
}

// f32 reg-staged fallbacks (compact ws)
__device__ inline void stage_sup_f32(const float* __restrict__ sup,
                                     const float* __restrict__ mean,
                                     int row0, int k0, unsigned short* lds) {
  const int tid = threadIdx.x;
#pragma unroll
  for (int it = 0; it < 4; ++it) {
    const int ci = it * 256 + tid;
    const int r = ci >> 3, kc = (ci & 7) << 3;
    const int c = row0 + r;
    const int k = k0 + kc;
    const int b = k >> 10, sp = k & 1023;
    const float4* g = (const float4*)(sup + ((size_t)b * CCH + c) * DSP + sp);
    const float4 v0 = g[0], v1 = g[1];
    const float m = mean[c];
    union { unsigned short h[8]; int4 q; } pk;
    pk.h[0] = f2bf(v0.x - m); pk.h[1] = f2bf(v0.y - m);
    pk.h[2] = f2bf(v0.z - m); pk.h[3] = f2bf(v0.w - m);
    pk.h[4] = f2bf(v1.x - m); pk.h[5] = f2bf(v1.y - m);
    pk.h[6] = f2bf(v1.z - m); pk.h[7] = f2bf(v1.w - m);
    *(int4*)(lds + (size_t)(r * 8 + ((ci & 7) ^ (r & 7))) * 8) = pk.q;
  }
}
__device__ inline void stage_q_f32(const float* __restrict__ qn,
                                   const float* __restrict__ qfacn,
                                   int row0, int k0, unsigned short* lds) {
  const int tid = threadIdx.x;
#pragma unroll
  for (int it = 0; it < 4; ++it) {
    const int ci = it * 256 + tid;
    const int r = ci >> 3, kc = (ci & 7) << 3;
    const int c = row0 + r;
    const float4* g = (const float4*)(qn + (size_t)c * DSP + k0 + kc);
    const float4 v0 = g[0], v1 = g[1];
    const float f = qfacn[c];
    union { unsigned short h[8]; int4 q; } pk;
    pk.h[0] = f2bf(v0.x * f); pk.h[1] = f2bf(v0.y * f);
    pk.h[2] = f2bf(v0.z * f); pk.h[3] = f2bf(v0.w * f);
    pk.h[4] = f2bf(v1.x * f); pk.h[5] = f2bf(v1.y * f);
    pk.h[6] = f2bf(v1.z * f); pk.h[7] = f2bf(v1.w * f);
    *(int4*)(lds + (size_t)(r * 8 + ((ci & 7) ^ (r & 7))) * 8) = pk.q;
  }
}
__device__ inline void compute_step(const unsigned short* lA, const unsigned short* lB,
                                    int wr, int wc, int lr, int kg, f32x4 acc[4][4]) {
  const int sc = (lr & 7) << 3;
#pragma unroll
  for (int kk = 0; kk < 64; kk += 32) {
    const int col = (kk + kg) ^ sc;
    bf16x8 a[4], b[4];
    rd4(lA, wr, col, lr, a);
    rd4(lB, wc, col, lr, b);
    mfma16(a, b, (f32x4(*)[4])acc);
#pragma unroll
    for (int i = 0; i < 4; ++i)
#pragma unroll
      for (int j = 0; j < 4; ++j) (void)0;
  }
}

__device__ inline void decode_tile(int t, int& ti, int& tj) {
  int rem = t; ti = 0;
  while (rem >= 8 - ti) { rem -= 8 - ti; ++ti; }
  tj = ti + rem;
}

// ---------------- cov = centered @ centered^T / (N-1+eps), upper tiles only ----------------
// 1-D grid 288 = 36 pairs x 8 kslices (ks = wg&7 -> XCD-local Sb slice).
// bf16 path: counted-vmcnt pipeline, 2 barriers per K-tile, 64 KB LDS.
template <bool F32>
__global__ __launch_bounds__(256) void cov_kernel(
    const unsigned short* __restrict__ Sb, const float* __restrict__ sup,
    const float* __restrict__ mean, float* __restrict__ cov) {
  __shared__ unsigned short clds[32768];   // 2 bufs x (A 8192 | B 8192) elems = 64 KB
  const int wg = blockIdx.x;
  const int ks = wg & 7;
  int ti, tj; decode_tile(wg >> 3, ti, tj);
  const bool diag = (ti == tj);
  const int tid = threadIdx.x, l = tid & 63, w = tid >> 6;
  const int wr = (w >> 1) * 64, wc = (w & 1) * 64, lr = l & 15, kg = (l >> 4) * 8;
  const int sw = (lr & 7) << 3;
  f32x4 acc[4][4];
#pragma unroll
  for (int i = 0; i < 4; ++i)
#pragma unroll
    for (int j = 0; j < 4; ++j) acc[i][j] = 0.f;

  const int kbase = ks * (NSUP / KSLICES);

  if (F32) {
    // reg-staged fallback, classic double-buffered loop
    unsigned short* lA0 = clds;            // reuse as [2][8192] pairs
    stage_sup_f32(sup, mean, ti * 128, kbase, lA0);
    if (!diag) stage_sup_f32(sup, mean, tj * 128, kbase, lA0 + 8192);
    __syncthreads();
    for (int kt = 0; kt < NK_COV; ++kt) {
      const int cb = (kt & 1) * 16384;
      const int nb = cb ^ 16384;
      if (kt + 1 < NK_COV) {
        const int k1 = kbase + (kt + 1) * 64;
        stage_sup_f32(sup, mean, ti * 128, k1, clds + nb);
        if (!diag) stage_sup_f32(sup, mean, tj * 128, k1, clds + nb + 8192);
      }
      compute_step(clds + cb, diag ? clds + cb : clds + cb + 8192, wr, wc, lr, kg, acc);
      __syncthreads();
    }
  } else {
    // prologue: tiles 0 and 1
    stage_glds(Sb, NSUP, ti * 128, kbase, clds);
    if (!diag) stage_glds(Sb, NSUP, tj * 128, kbase, clds + 8192);
    stage_glds(Sb, NSUP, ti * 128, kbase + 64, clds + 16384);
    if (!diag) stage_glds(Sb, NSUP, tj * 128, kbase + 64, clds + 16384 + 8192);
    for (int t = 0; t < NK_COV; ++t) {
      const int cb = (t & 1) * 16384;
      if (t < NK_COV - 1) { if (diag) { WAITVM(4); } else { WAITVM(8); } }
      else { WAITVM(0); }
      BAR(); SCHED0();
      const unsigned short* A = clds + cb;
      const unsigned short* B = diag ? A : A + 8192;
      bf16x8 a[4], b[4];
      {
        const int col = kg ^ sw;
        rd4(A, wr, col, lr, a);
        rd4(B, wc, col, lr, b);
        mfma16(a, b, (f32x4(*)[4])acc);
      }
      {
        const int col = (32 + kg) ^ sw;
        rd4(A, wr, col, lr, a);
        rd4(B, wc, col, lr, b);
        WAITLGKM0();
        BAR(); SCHED0();
        if (t + 2 < NK_COV) {
          const int k2 = kbase + (t + 2) * 64;
          stage_glds(Sb, NSUP, ti * 128, k2, clds + cb);
          if (!diag) stage_glds(Sb, NSUP, tj * 128, k2, clds + cb + 8192);
        }
        mfma16(a, b, (f32x4(*)[4])acc);
      }
    }
  }

  const float scale = 1.0f / (25599.0f + 1e-8f);
  const int rbase = ti * 128 + wr + (l >> 4) * 4;
  const int cbase = tj * 128 + wc + (l & 15);
#pragma unroll
  for (int i = 0; i < 4; ++i)
#pragma unroll
    for (int j = 0; j < 4; ++j)
#pragma unroll
      for (int r = 0; r < 4; ++r)
        atomicAdd(&cov[(size_t)(rbase + i * 16 + r) * CCH + cbase + j * 16],
                  acc[i][j][r] * scale);
}

// ---------------- fallback (thin ws) 128-tile gram ----------------
__global__ __launch_bounds__(256) void gram_kernel_f32(
    const float* __restrict__ q, const float* __restrict__ qfac,
    const float* __restrict__ cov, float* __restrict__ out) {
  __shared__ unsigned short lA[2][128 * 64];
  __shared__ unsigned short lB[2][128 * 64];
  const int wg = blockIdx.x;
  const int xcd = wg & 7, slot = wg >> 3;
  const int n = xcd * 8 + slot / 36;
  int ti, tj; decode_tile(slot % 36, ti, tj);
  const bool diag = (ti == tj);
  const int tid = threadIdx.x, l = tid & 63, w = tid >> 6;
  const int wr = (w >> 1) * 64, wc = (w & 1) * 64, lr = l & 15, kg = (l >> 4) * 8;
  f32x4 acc[4][4];
#pragma unroll
  for (int i = 0; i < 4; ++i)
#pragma unroll
    for (int j = 0; j < 4; ++j) acc[i][j] = 0.f;

  const float* qn = q + (size_t)n * CCH * DSP;
  const float* qfacn = qfac + (size_t)n * CCH;

  stage_q_f32(qn, qfacn, ti * 128, 0, lA[0]);
  if (!diag) stage_q_f32(qn, qfacn, tj * 128, 0, lB[0]);
  __syncthreads();
  int cur = 0;
  for (int kt = 0; kt < 16; ++kt) {
    if (kt + 1 < 16) {
      const int k1 = (kt + 1) * 64;
      stage_q_f32(qn, qfacn, ti * 128, k1, lA[cur ^ 1]);
      if (!diag) stage_q_f32(qn, qfacn, tj * 128, k1, lB[cur ^ 1]);
    }
    compute_step(lA[cur], diag ? lA[cur] : lB[cur], wr, wc, lr, kg, acc);
    __syncthreads();
    cur ^= 1;
  }

  float s = 0.f;
  const int rbase = ti * 128 + wr + (l >> 4) * 4;
  const int cbase = tj * 128 + wc + (l & 15);
#pragma unroll
  for (int i = 0; i < 4; ++i)
#pragma unroll
    for (int j = 0; j < 4; ++j)
#pragma unroll
      for (int r = 0; r < 4; ++r)
        s += acc[i][j][r] * cov[(size_t)(rbase + i * 16 + r) * CCH + cbase + j * 16];
  if (!diag) s *= 2.0f;
  s *= (1.0f / 1024.0f);
#pragma unroll
  for (int off = 32; off > 0; off >>= 1) s += __shfl_xor(s, off);
  if (l == 0) atomicAdd(&out[n], s);
}

// ---------------- 256x256 8-wave gram, counted-vmcnt pipeline ----------------
// LDS 128 KB: buf b at b*32768 elems: A [0,16384), B [16384,32768).
// 2 barriers per K-tile; stage(t+2) issued mid-tile after the freeing barrier;
// WAITVM(8) at tile top keeps next tile's loads in flight (full-tile prefetch).
__global__ __launch_bounds__(512, 2) void gram256_kernel(
    const unsigned short* __restrict__ Qb, const float* __restrict__ cov,
    float* __restrict__ out) {
  __shared__ unsigned short lds[65536];   // 128 KB
  const int wg = blockIdx.x;
  const int xcd = wg & 7, slot = wg >> 3;        // slot 0..79
  const int n = xcd * 8 + slot / 10;
  int rem = slot % 10, ti = 0;
  while (rem >= 4 - ti) { rem -= 4 - ti; ++ti; }
  const int tj = ti + rem;
  const bool diag = (ti == tj);
  const int tid = threadIdx.x, l = tid & 63, wid = tid >> 6;
  const int wm = wid >> 2, wn = wid & 3;
  const int lr = l & 15, kg = (l >> 4) * 8;
  const int sw = (lr & 7) << 3;
  const unsigned short* Qn = Qb + (size_t)n * CCH * DSP;

  f32x4 acc[8][4];
#pragma unroll
  for (int i = 0; i < 8; ++i)
#pragma unroll
    for (int j = 0; j < 4; ++j) acc[i][j] = 0.f;

  // prologue: stage tiles 0 and 1
  stage256(Qn, ti * 256, 0, lds);
  if (!diag) stage256(Qn, tj * 256, 0, lds + 16384);
  stage256(Qn, ti * 256, 64, lds + 32768);
  if (!diag) stage256(Qn, tj * 256, 64, lds + 32768 + 16384);

  for (int t = 0; t < 16; ++t) {
    const int cb = (t & 1) << 15;
    if (t < 15) { if (diag) { WAITVM(4); } else { WAITVM(8); } }
    else { WAITVM(0); }
    BAR(); SCHED0();
    const unsigned short* A = lds + cb + wm * 8192;
    const unsigned short* B = lds + cb + (diag ? 0 : 16384) + (wn >> 1) * 8192;
    const int brow = (wn & 1) * 64;
    bf16x8 a[4], b[4];
    {
      const int col = kg ^ sw;
      rd4(B, brow, col, lr, b);
      rd4(A, 0, col, lr, a);
      mfma16(a, b, &acc[0]);
      rd4(A, 64, col, lr, a);
      mfma16(a, b, &acc[4]);
    }
    {
      const int col = (32 + kg) ^ sw;
      rd4(B, brow, col, lr, b);
      rd4(A, 0, col, lr, a);
      mfma16(a, b, &acc[0]);
      rd4(A, 64, col, lr, a);
      WAITLGKM0();
      BAR(); SCHED0();                   // all waves done reading buf cb
      if (t + 2 < 16) {
        stage256(Qn, ti * 256, (t + 2) * 64, lds + cb);
        if (!diag) stage256(Qn, tj * 256, (t + 2) * 64, lds + cb + 16384);
      }
      mfma16(a, b, &acc[4]);
    }
  }

  float s = 0.f;
  const int rbase = ti * 256 + wm * 128 + (l >> 4) * 4;
  const int cbase = tj * 256 + wn * 64 + (l & 15);
#pragma unroll
  for (int i = 0; i < 8; ++i)
#pragma unroll
    for (int j = 0; j < 4; ++j)
#pragma unroll
      for (int r = 0; r < 4; ++r)
        s += acc[i][j][r] * cov[(size_t)(rbase + i * 16 + r) * CCH + cbase + j * 16];
  if (!diag) s *= 2.0f;
  s *= (1.0f / 1024.0f);
#pragma unroll
  for (int off = 32; off > 0; off >>= 1) s += __shfl_xor(s, off);
  if (l == 0) atomicAdd(&out[n], s);
}

// ---------------- launch ----------------
extern "C" void kernel_launch(void* const* d_in, const int* in_sizes, int n_in,
                              void* d_out, int out_size, void* d_ws, size_t ws_size,
                              hipStream_t stream) {
  const float* q = (const float*)d_in[0];
  const float* sup = (const float*)d_in[1];
  float* out = (float*)d_out;

  char* ws = (char*)d_ws;
  float* mean = (float*)ws;                                  // 4 KB
  float* qfac = (float*)(ws + (4 << 10));                    // 256 KB
  float* cov  = (float*)(ws + (4 << 10) + (256 << 10));      // 4 MB
  unsigned short* Sb = (unsigned short*)(ws + (4 << 10) + (256 << 10) + (4 << 20));
  unsigned short* Qb = Sb + (size_t)CCH * NSUP;
  const size_t need_fat = (size_t)(4 << 10) + (256 << 10) + (4 << 20) +
                          (size_t)CCH * NSUP * 2 + (size_t)NQ * CCH * DSP * 2;
  const bool fat = ws_size >= need_fat;

  zero_kernel<<<1024, 256, 0, stream>>>((float4*)cov, (float4*)out);

  mean_center_kernel<<<CCH, 512, 0, stream>>>(sup, mean, Sb, fat ? 1 : 0);
  qnorm_kernel<<<NQ * CCH / 4, 256, 0, stream>>>(q, qfac, Qb, fat ? 1 : 0);

  if (fat) {
    cov_kernel<false><<<dim3(288), 256, 0, stream>>>(Sb, sup, mean, cov);
    gram256_kernel<<<dim3(640), 512, 0, stream>>>(Qb, cov, out);
  } else {
    cov_kernel<true><<<dim3(288), 256, 0, stream>>>(Sb, sup, mean, cov);
    gram_kernel_f32<<<dim3(8 * 8 * 36), 256, 0, stream>>>(q, qfac, cov, out);
  }
}